// Round 1
// baseline (2078.315 us; speedup 1.0000x reference)
//
#include <hip/hip_runtime.h>
#include <hip/hip_bf16.h>
#include <math.h>

typedef unsigned short u16;
typedef unsigned int u32;
typedef __bf16 bf16x8 __attribute__((ext_vector_type(8)));
typedef float f32x4 __attribute__((ext_vector_type(4)));

#define MROWS 100352   // 32 * 56 * 56
#define CDIM 512
#define SCALE_ATTN 0.17677669529663687f

__device__ __forceinline__ u16 f2bf(float f) {
    u32 u = __float_as_uint(f);
    u32 r = (u + 0x7fffu + ((u >> 16) & 1u)) >> 16;   // RNE
    return (u16)r;
}
__device__ __forceinline__ float bf2f(u16 h) {
    return __uint_as_float(((u32)h) << 16);
}

// ---------------- transpose + cast: fp32 W[K][N] -> bf16 WT[N][K] ----------------
__global__ void transpose_cast(const float* __restrict__ W, u16* __restrict__ WT, int K, int N) {
    int idx = blockIdx.x * 256 + threadIdx.x;
    if (idx >= K * N) return;
    int k = idx / N, n = idx % N;
    WT[(size_t)n * K + k] = f2bf(W[idx]);
}

// ---------------- LayerNorm fp32 -> bf16, one wave per row (C=512) ----------------
__global__ __launch_bounds__(256) void ln_kernel(const float* __restrict__ x, const float* __restrict__ g,
                                                 const float* __restrict__ bta, u16* __restrict__ out) {
    int row = blockIdx.x * 4 + (threadIdx.x >> 6);
    int lane = threadIdx.x & 63;
    const float* xr = x + (size_t)row * CDIM + lane * 8;
    float4 v0 = *(const float4*)xr;
    float4 v1 = *(const float4*)(xr + 4);
    float xv[8] = {v0.x, v0.y, v0.z, v0.w, v1.x, v1.y, v1.z, v1.w};
    float s = 0.f, ss = 0.f;
#pragma unroll
    for (int i = 0; i < 8; ++i) { s += xv[i]; ss += xv[i] * xv[i]; }
#pragma unroll
    for (int o = 1; o < 64; o <<= 1) { s += __shfl_xor(s, o); ss += __shfl_xor(ss, o); }
    float mu = s * (1.f / CDIM);
    float var = ss * (1.f / CDIM) - mu * mu;
    float rs = rsqrtf(var + 1e-6f);
    int c = lane * 8;
    u32 pk[4];
#pragma unroll
    for (int i = 0; i < 4; ++i) {
        float y0 = (xv[2 * i] - mu) * rs * g[c + 2 * i] + bta[c + 2 * i];
        float y1 = (xv[2 * i + 1] - mu) * rs * g[c + 2 * i + 1] + bta[c + 2 * i + 1];
        pk[i] = (u32)f2bf(y0) | ((u32)f2bf(y1) << 16);
    }
    uint4 ov; ov.x = pk[0]; ov.y = pk[1]; ov.z = pk[2]; ov.w = pk[3];
    *(uint4*)(out + (size_t)row * CDIM + c) = ov;
}

// ---------------- bf16 GEMM, m97 structure: C[M,N] = A[M,K] * BT[N,K]^T ----------------
#define BM 128
#define BN 128
#define BK 64

enum { EPI_BF16 = 0, EPI_GELU_BF16 = 1, EPI_RES_F32 = 2 };

__device__ __forceinline__ void gload_lds16(const void* g, void* l) {
    __builtin_amdgcn_global_load_lds(
        (const __attribute__((address_space(1))) u32*)g,
        (__attribute__((address_space(3))) u32*)l, 16, 0, 0);
}

template <int EPI>
__global__ __launch_bounds__(256) void gemm_bt(const u16* __restrict__ A, const u16* __restrict__ BT,
                                               const float* __restrict__ bias, const float* __restrict__ res,
                                               void* __restrict__ outp, int M, int N, int K) {
    __shared__ __align__(16) u16 As[BM * BK];
    __shared__ __align__(16) u16 Bs[BN * BK];
    const int t = threadIdx.x;
    const int lane = t & 63;
    const int w = t >> 6;
    const int wr = w >> 1, wc = w & 1;
    const int m0 = blockIdx.x * BM;
    const int n0 = blockIdx.y * BN;

    f32x4 acc[4][4] = {};

    const int r15 = lane & 15;
    const int khalf = (lane >> 4) << 3;

    for (int kt = 0; kt < K; kt += BK) {
#pragma unroll
        for (int i = 0; i < 4; ++i) {
            int vi = i * 256 + t;
            int row = vi >> 3;
            int col = (vi & 7) << 3;
            int lbase = (i * 256 + w * 64) << 3;  // wave-uniform LDS element base
            gload_lds16(A + (size_t)(m0 + row) * K + kt + col, &As[lbase]);
            gload_lds16(BT + (size_t)(n0 + row) * K + kt + col, &Bs[lbase]);
        }
        __syncthreads();
#pragma unroll
        for (int kk = 0; kk < BK; kk += 32) {
            bf16x8 af[4], bfr[4];
            int kof = kk + khalf;
#pragma unroll
            for (int mi = 0; mi < 4; ++mi)
                af[mi] = *(const bf16x8*)&As[(wr * 64 + mi * 16 + r15) * BK + kof];
#pragma unroll
            for (int ni = 0; ni < 4; ++ni)
                bfr[ni] = *(const bf16x8*)&Bs[(wc * 64 + ni * 16 + r15) * BK + kof];
#pragma unroll
            for (int mi = 0; mi < 4; ++mi)
#pragma unroll
                for (int ni = 0; ni < 4; ++ni)
                    acc[mi][ni] = __builtin_amdgcn_mfma_f32_16x16x32_bf16(af[mi], bfr[ni], acc[mi][ni], 0, 0, 0);
        }
        __syncthreads();
    }

    const int rowbase = m0 + wr * 64 + ((lane >> 4) << 2);
#pragma unroll
    for (int ni = 0; ni < 4; ++ni) {
        int col = n0 + wc * 64 + ni * 16 + r15;
        float bv = bias[col];
#pragma unroll
        for (int mi = 0; mi < 4; ++mi) {
#pragma unroll
            for (int j = 0; j < 4; ++j) {
                int row = rowbase + mi * 16 + j;
                float v = acc[mi][ni][j] + bv;
                if (EPI == EPI_GELU_BF16) v = 0.5f * v * (1.f + erff(v * 0.70710678118654752f));
                if (EPI == EPI_RES_F32) {
                    size_t o = (size_t)row * N + col;
                    ((float*)outp)[o] = v + res[o];
                } else {
                    ((u16*)outp)[(size_t)row * N + col] = f2bf(v);
                }
            }
        }
    }
}

// ---------------- windowed attention: one wave per (window, head) ----------------
// qkv: [MROWS][1536] bf16, columns = qkv_idx*512 + head*32 + d (natural row order)
// aout: [MROWS][512] bf16
__global__ __launch_bounds__(64) void attn_kernel(const u16* __restrict__ qkv, u16* __restrict__ aout) {
    __shared__ float Ks[49 * 32];
    __shared__ float Vs[49 * 32];
    const int wdw = blockIdx.x;
    const int h = blockIdx.y;
    const int t = threadIdx.x;
    const int b = wdw >> 6, wy = (wdw >> 3) & 7, wx = wdw & 7;

    int row = 0;
    float q[32];
    if (t < 49) {
        int py = t / 7, px = t % 7;
        row = b * 3136 + (wy * 7 + py) * 56 + (wx * 7 + px);
        const u16* bp = qkv + (size_t)row * 1536 + h * 32;
#pragma unroll
        for (int i = 0; i < 4; ++i) {
            uint4 uq = *(const uint4*)(bp + i * 8);
            uint4 uk = *(const uint4*)(bp + 512 + i * 8);
            uint4 uv = *(const uint4*)(bp + 1024 + i * 8);
            u32 qa[4] = {uq.x, uq.y, uq.z, uq.w};
            u32 ka[4] = {uk.x, uk.y, uk.z, uk.w};
            u32 va[4] = {uv.x, uv.y, uv.z, uv.w};
#pragma unroll
            for (int j = 0; j < 4; ++j) {
                q[i * 8 + 2 * j] = bf2f((u16)(qa[j] & 0xffffu));
                q[i * 8 + 2 * j + 1] = bf2f((u16)(qa[j] >> 16));
                Ks[t * 32 + i * 8 + 2 * j] = bf2f((u16)(ka[j] & 0xffffu));
                Ks[t * 32 + i * 8 + 2 * j + 1] = bf2f((u16)(ka[j] >> 16));
                Vs[t * 32 + i * 8 + 2 * j] = bf2f((u16)(va[j] & 0xffffu));
                Vs[t * 32 + i * 8 + 2 * j + 1] = bf2f((u16)(va[j] >> 16));
            }
        }
    }
    __syncthreads();
    if (t >= 49) return;

    float s[49];
    float mx = -1e30f;
    for (int m = 0; m < 49; ++m) {
        float acc = 0.f;
#pragma unroll
        for (int d = 0; d < 32; ++d) acc += q[d] * Ks[m * 32 + d];
        acc *= SCALE_ATTN;
        s[m] = acc;
        mx = fmaxf(mx, acc);
    }
    float sum = 0.f;
    for (int m = 0; m < 49; ++m) { float e = __expf(s[m] - mx); s[m] = e; sum += e; }
    float inv = 1.f / sum;
    float o[32];
#pragma unroll
    for (int d = 0; d < 32; ++d) o[d] = 0.f;
    for (int m = 0; m < 49; ++m) {
        float p = s[m] * inv;
#pragma unroll
        for (int d = 0; d < 32; ++d) o[d] += p * Vs[m * 32 + d];
    }
    u16* op = aout + (size_t)row * 512 + h * 32;
#pragma unroll
    for (int i = 0; i < 4; ++i) {
        uint4 ov;
        ov.x = (u32)f2bf(o[i * 8 + 0]) | ((u32)f2bf(o[i * 8 + 1]) << 16);
        ov.y = (u32)f2bf(o[i * 8 + 2]) | ((u32)f2bf(o[i * 8 + 3]) << 16);
        ov.z = (u32)f2bf(o[i * 8 + 4]) | ((u32)f2bf(o[i * 8 + 5]) << 16);
        ov.w = (u32)f2bf(o[i * 8 + 6]) | ((u32)f2bf(o[i * 8 + 7]) << 16);
        *(uint4*)(op + i * 8) = ov;
    }
}

// ---------------- launch ----------------
extern "C" void kernel_launch(void* const* d_in, const int* in_sizes, int n_in,
                              void* d_out, int out_size, void* d_ws, size_t ws_size,
                              hipStream_t stream) {
    (void)in_sizes; (void)n_in; (void)out_size; (void)ws_size;
    const float* x      = (const float*)d_in[0];
    const float* ln1_g  = (const float*)d_in[1];
    const float* ln1_b  = (const float*)d_in[2];
    const float* qkv_w  = (const float*)d_in[3];
    const float* qkv_b  = (const float*)d_in[4];
    const float* proj_w = (const float*)d_in[5];
    const float* proj_b = (const float*)d_in[6];
    const float* ln2_g  = (const float*)d_in[7];
    const float* ln2_b  = (const float*)d_in[8];
    const float* mlp_w1 = (const float*)d_in[9];
    const float* mlp_b1 = (const float*)d_in[10];
    const float* mlp_w2 = (const float*)d_in[11];
    const float* mlp_b2 = (const float*)d_in[12];
    float* out = (float*)d_out;

    const int M = MROWS;
    char* ws = (char*)d_ws;
    // region sizes (bytes)
    const size_t SZ_H   = (size_t)M * 512 * 2;   // 102,760,448  (h / attn_out / h2)
    const size_t SZ_X2  = (size_t)M * 512 * 4;   // 205,520,896  (x2 fp32)
    const size_t SZ_BIG = (size_t)M * 2048 * 2;  // 411,041,792  (qkv / mlp mid)
    u16*   h    = (u16*)ws;
    float* x2   = (float*)(ws + SZ_H);
    u16*   big  = (u16*)(ws + SZ_H + SZ_X2);
    u16*   qkv_wT  = (u16*)(ws + SZ_H + SZ_X2 + SZ_BIG);
    u16*   proj_wT = qkv_wT + 1536 * 512;
    u16*   w1T     = proj_wT + 512 * 512;
    u16*   w2T     = w1T + 2048 * 512;

    // 1) weight transposes to bf16 (N,K)
    transpose_cast<<<(512 * 1536 + 255) / 256, 256, 0, stream>>>(qkv_w, qkv_wT, 512, 1536);
    transpose_cast<<<(512 * 512 + 255) / 256, 256, 0, stream>>>(proj_w, proj_wT, 512, 512);
    transpose_cast<<<(512 * 2048 + 255) / 256, 256, 0, stream>>>(mlp_w1, w1T, 512, 2048);
    transpose_cast<<<(2048 * 512 + 255) / 256, 256, 0, stream>>>(mlp_w2, w2T, 2048, 512);

    // 2) LN1: x -> h (bf16)
    ln_kernel<<<M / 4, 256, 0, stream>>>(x, ln1_g, ln1_b, h);

    // 3) qkv = h @ qkv_w + b  -> big (bf16, M x 1536)
    gemm_bt<EPI_BF16><<<dim3(M / BM, 1536 / BN), 256, 0, stream>>>(h, qkv_wT, qkv_b, nullptr, big, M, 1536, 512);

    // 4) windowed attention -> h (bf16, M x 512), window permutation folded into row indexing
    attn_kernel<<<dim3(2048, 16), 64, 0, stream>>>(big, h);

    // 5) x2 = attn @ proj_w + b + x  (fp32)
    gemm_bt<EPI_RES_F32><<<dim3(M / BM, 512 / BN), 256, 0, stream>>>(h, proj_wT, proj_b, x, x2, M, 512, 512);

    // 6) LN2: x2 -> h (bf16)
    ln_kernel<<<M / 4, 256, 0, stream>>>(x2, ln2_g, ln2_b, h);

    // 7) mid = gelu(h @ w1 + b1) -> big (bf16, M x 2048)
    gemm_bt<EPI_GELU_BF16><<<dim3(M / BM, 2048 / BN), 256, 0, stream>>>(h, w1T, mlp_b1, nullptr, big, M, 2048, 512);

    // 8) out = mid @ w2 + b2 + x2  (fp32)
    gemm_bt<EPI_RES_F32><<<dim3(M / BM, 512 / BN), 256, 0, stream>>>(big, w2T, mlp_b2, x2, out, M, 512, 2048);
}

// Round 2
// 1922.394 us; speedup vs baseline: 1.0811x; 1.0811x over previous
//
#include <hip/hip_runtime.h>
#include <hip/hip_bf16.h>
#include <math.h>

typedef unsigned short u16;
typedef unsigned int u32;
typedef __bf16 bf16x8 __attribute__((ext_vector_type(8)));
typedef float f32x4 __attribute__((ext_vector_type(4)));

#define MROWS 100352   // 32 * 56 * 56
#define CDIM 512
#define SCALE_ATTN 0.17677669529663687f

__device__ __forceinline__ u16 f2bf(float f) {
    u32 u = __float_as_uint(f);
    u32 r = (u + 0x7fffu + ((u >> 16) & 1u)) >> 16;   // RNE
    return (u16)r;
}
__device__ __forceinline__ float bf2f(u16 h) {
    return __uint_as_float(((u32)h) << 16);
}

// ---------------- transpose + cast: fp32 W[K][N] -> bf16 WT[N][K] ----------------
__global__ void transpose_cast(const float* __restrict__ W, u16* __restrict__ WT, int K, int N) {
    int idx = blockIdx.x * 256 + threadIdx.x;
    if (idx >= K * N) return;
    int k = idx / N, n = idx % N;
    WT[(size_t)n * K + k] = f2bf(W[idx]);
}

// ---------------- LayerNorm fp32 -> bf16, one wave per row (C=512) ----------------
__global__ __launch_bounds__(256) void ln_kernel(const float* __restrict__ x, const float* __restrict__ g,
                                                 const float* __restrict__ bta, u16* __restrict__ out) {
    int row = blockIdx.x * 4 + (threadIdx.x >> 6);
    int lane = threadIdx.x & 63;
    const float* xr = x + (size_t)row * CDIM + lane * 8;
    float4 v0 = *(const float4*)xr;
    float4 v1 = *(const float4*)(xr + 4);
    float xv[8] = {v0.x, v0.y, v0.z, v0.w, v1.x, v1.y, v1.z, v1.w};
    float s = 0.f, ss = 0.f;
#pragma unroll
    for (int i = 0; i < 8; ++i) { s += xv[i]; ss += xv[i] * xv[i]; }
#pragma unroll
    for (int o = 1; o < 64; o <<= 1) { s += __shfl_xor(s, o); ss += __shfl_xor(ss, o); }
    float mu = s * (1.f / CDIM);
    float var = ss * (1.f / CDIM) - mu * mu;
    float rs = rsqrtf(var + 1e-6f);
    int c = lane * 8;
    u32 pk[4];
#pragma unroll
    for (int i = 0; i < 4; ++i) {
        float y0 = (xv[2 * i] - mu) * rs * g[c + 2 * i] + bta[c + 2 * i];
        float y1 = (xv[2 * i + 1] - mu) * rs * g[c + 2 * i + 1] + bta[c + 2 * i + 1];
        pk[i] = (u32)f2bf(y0) | ((u32)f2bf(y1) << 16);
    }
    uint4 ov; ov.x = pk[0]; ov.y = pk[1]; ov.z = pk[2]; ov.w = pk[3];
    *(uint4*)(out + (size_t)row * CDIM + c) = ov;
}

// ---------------- bf16 GEMM: C[M,N] = A[M,K] * BT[N,K]^T ----------------
// 128x128 tile, BK=64, 4 waves. LDS tiles are XOR-swizzled (element ^= (row&7)<<3),
// realized by pre-swizzling the GLOBAL source column (global_load_lds dest is linear)
// and applying the same XOR on the ds_read side.
#define BM 128
#define BN 128
#define BK 64

enum { EPI_BF16 = 0, EPI_GELU_BF16 = 1, EPI_RES_F32 = 2 };

__device__ __forceinline__ void gload_lds16(const void* g, void* l) {
    __builtin_amdgcn_global_load_lds(
        (const __attribute__((address_space(1))) u32*)g,
        (__attribute__((address_space(3))) u32*)l, 16, 0, 0);
}

template <int EPI>
__global__ __launch_bounds__(256) void gemm_bt(const u16* __restrict__ A, const u16* __restrict__ BT,
                                               const float* __restrict__ bias, const float* __restrict__ res,
                                               void* __restrict__ outp, int M, int N, int K, int nnb) {
    __shared__ __align__(16) char smem[32768];
    u16* As = (u16*)smem;               // 128*64*2 = 16KB
    u16* Bs = (u16*)(smem + 16384);     // 16KB

    const int t = threadIdx.x;
    const int lane = t & 63;
    const int w = t >> 6;
    const int wr = w >> 1, wc = w & 1;

    // XCD-bijective swizzle (nwg % 8 == 0 for all shapes here), then A-panel-major:
    // consecutive wgids within an XCD chunk share the same M-block (A tile L2 reuse).
    const int nwg = gridDim.x;
    const int chunk = nwg >> 3;
    const int wg = (blockIdx.x & 7) * chunk + (blockIdx.x >> 3);
    const int m0 = (wg / nnb) * BM;
    const int n0 = (wg % nnb) * BN;

    f32x4 acc[4][4] = {};

    const int r15 = lane & 15;
    const int khalf = (lane >> 4) << 3;
    const int xorv = (r15 & 7) << 3;    // read-side XOR (row&7)<<3, row%8 == r15%8

    for (int kt = 0; kt < K; kt += BK) {
#pragma unroll
        for (int i = 0; i < 4; ++i) {
            int vi = i * 256 + t;
            int row = vi >> 3;
            int col = (((vi & 7) ^ (row & 7)) << 3);      // pre-swizzled global column
            int lbase = (i * 256 + w * 64) << 3;          // wave-uniform linear LDS dest
            gload_lds16(A + (size_t)(m0 + row) * K + kt + col, &As[lbase]);
            gload_lds16(BT + (size_t)(n0 + row) * K + kt + col, &Bs[lbase]);
        }
        __syncthreads();
#pragma unroll
        for (int kk = 0; kk < BK; kk += 32) {
            bf16x8 af[4], bfr[4];
            int kof = (kk + khalf) ^ xorv;
#pragma unroll
            for (int mi = 0; mi < 4; ++mi)
                af[mi] = *(const bf16x8*)&As[(wr * 64 + mi * 16 + r15) * BK + kof];
#pragma unroll
            for (int ni = 0; ni < 4; ++ni)
                bfr[ni] = *(const bf16x8*)&Bs[(wc * 64 + ni * 16 + r15) * BK + kof];
#pragma unroll
            for (int mi = 0; mi < 4; ++mi)
#pragma unroll
                for (int ni = 0; ni < 4; ++ni)
                    acc[mi][ni] = __builtin_amdgcn_mfma_f32_16x16x32_bf16(af[mi], bfr[ni], acc[mi][ni], 0, 0, 0);
        }
        __syncthreads();
    }

    // ---- coalesced epilogue: per-wave LDS staging (16 rows x 72-padded floats) ----
    float* ep = (float*)smem + w * (16 * 72);   // 4 waves * 4608B = 18432B <= 32KB
    const int lg = lane >> 4;
#pragma unroll
    for (int mi = 0; mi < 4; ++mi) {
        __syncthreads();
#pragma unroll
        for (int ni = 0; ni < 4; ++ni)
#pragma unroll
            for (int j = 0; j < 4; ++j)
                ep[(lg * 4 + j) * 72 + ni * 16 + r15] = acc[mi][ni][j];
        __syncthreads();
#pragma unroll
        for (int p = 0; p < 4; ++p) {
            int lr = p * 4 + lg;
            f32x4 v = *(f32x4*)&ep[lr * 72 + r15 * 4];
            int grow = m0 + wr * 64 + mi * 16 + lr;
            int gcol = n0 + wc * 64 + r15 * 4;
            float4 bv = *(const float4*)&bias[gcol];
            float o0 = v[0] + bv.x, o1 = v[1] + bv.y, o2 = v[2] + bv.z, o3 = v[3] + bv.w;
            if (EPI == EPI_GELU_BF16) {
                o0 = 0.5f * o0 * (1.f + erff(o0 * 0.70710678118654752f));
                o1 = 0.5f * o1 * (1.f + erff(o1 * 0.70710678118654752f));
                o2 = 0.5f * o2 * (1.f + erff(o2 * 0.70710678118654752f));
                o3 = 0.5f * o3 * (1.f + erff(o3 * 0.70710678118654752f));
            }
            if (EPI == EPI_RES_F32) {
                size_t off = (size_t)grow * N + gcol;
                float4 rv = *(const float4*)&res[off];
                float4 ov = make_float4(o0 + rv.x, o1 + rv.y, o2 + rv.z, o3 + rv.w);
                *(float4*)((float*)outp + off) = ov;
            } else {
                uint2 ov;
                ov.x = (u32)f2bf(o0) | ((u32)f2bf(o1) << 16);
                ov.y = (u32)f2bf(o2) | ((u32)f2bf(o3) << 16);
                *(uint2*)((u16*)outp + (size_t)grow * N + gcol) = ov;
            }
        }
    }
}

// ---------------- windowed attention: one wave per (window, head) ----------------
__global__ __launch_bounds__(64) void attn_kernel(const u16* __restrict__ qkv, u16* __restrict__ aout) {
    __shared__ float Ks[49 * 32];
    __shared__ float Vs[49 * 32];
    const int wdw = blockIdx.x;
    const int h = blockIdx.y;
    const int t = threadIdx.x;
    const int b = wdw >> 6, wy = (wdw >> 3) & 7, wx = wdw & 7;

    int row = 0;
    float q[32];
    if (t < 49) {
        int py = t / 7, px = t % 7;
        row = b * 3136 + (wy * 7 + py) * 56 + (wx * 7 + px);
        const u16* bp = qkv + (size_t)row * 1536 + h * 32;
#pragma unroll
        for (int i = 0; i < 4; ++i) {
            uint4 uq = *(const uint4*)(bp + i * 8);
            uint4 uk = *(const uint4*)(bp + 512 + i * 8);
            uint4 uv = *(const uint4*)(bp + 1024 + i * 8);
            u32 qa[4] = {uq.x, uq.y, uq.z, uq.w};
            u32 ka[4] = {uk.x, uk.y, uk.z, uk.w};
            u32 va[4] = {uv.x, uv.y, uv.z, uv.w};
#pragma unroll
            for (int j = 0; j < 4; ++j) {
                q[i * 8 + 2 * j] = bf2f((u16)(qa[j] & 0xffffu));
                q[i * 8 + 2 * j + 1] = bf2f((u16)(qa[j] >> 16));
                Ks[t * 32 + i * 8 + 2 * j] = bf2f((u16)(ka[j] & 0xffffu));
                Ks[t * 32 + i * 8 + 2 * j + 1] = bf2f((u16)(ka[j] >> 16));
                Vs[t * 32 + i * 8 + 2 * j] = bf2f((u16)(va[j] & 0xffffu));
                Vs[t * 32 + i * 8 + 2 * j + 1] = bf2f((u16)(va[j] >> 16));
            }
        }
    }
    __syncthreads();
    if (t >= 49) return;

    float s[49];
    float mx = -1e30f;
    for (int m = 0; m < 49; ++m) {
        float acc = 0.f;
#pragma unroll
        for (int d = 0; d < 32; ++d) acc += q[d] * Ks[m * 32 + d];
        acc *= SCALE_ATTN;
        s[m] = acc;
        mx = fmaxf(mx, acc);
    }
    float sum = 0.f;
    for (int m = 0; m < 49; ++m) { float e = __expf(s[m] - mx); s[m] = e; sum += e; }
    float inv = 1.f / sum;
    float o[32];
#pragma unroll
    for (int d = 0; d < 32; ++d) o[d] = 0.f;
    for (int m = 0; m < 49; ++m) {
        float p = s[m] * inv;
#pragma unroll
        for (int d = 0; d < 32; ++d) o[d] += p * Vs[m * 32 + d];
    }
    u16* op = aout + (size_t)row * 512 + h * 32;
#pragma unroll
    for (int i = 0; i < 4; ++i) {
        uint4 ov;
        ov.x = (u32)f2bf(o[i * 8 + 0]) | ((u32)f2bf(o[i * 8 + 1]) << 16);
        ov.y = (u32)f2bf(o[i * 8 + 2]) | ((u32)f2bf(o[i * 8 + 3]) << 16);
        ov.z = (u32)f2bf(o[i * 8 + 4]) | ((u32)f2bf(o[i * 8 + 5]) << 16);
        ov.w = (u32)f2bf(o[i * 8 + 6]) | ((u32)f2bf(o[i * 8 + 7]) << 16);
        *(uint4*)(op + i * 8) = ov;
    }
}

// ---------------- launch ----------------
extern "C" void kernel_launch(void* const* d_in, const int* in_sizes, int n_in,
                              void* d_out, int out_size, void* d_ws, size_t ws_size,
                              hipStream_t stream) {
    (void)in_sizes; (void)n_in; (void)out_size; (void)ws_size;
    const float* x      = (const float*)d_in[0];
    const float* ln1_g  = (const float*)d_in[1];
    const float* ln1_b  = (const float*)d_in[2];
    const float* qkv_w  = (const float*)d_in[3];
    const float* qkv_b  = (const float*)d_in[4];
    const float* proj_w = (const float*)d_in[5];
    const float* proj_b = (const float*)d_in[6];
    const float* ln2_g  = (const float*)d_in[7];
    const float* ln2_b  = (const float*)d_in[8];
    const float* mlp_w1 = (const float*)d_in[9];
    const float* mlp_b1 = (const float*)d_in[10];
    const float* mlp_w2 = (const float*)d_in[11];
    const float* mlp_b2 = (const float*)d_in[12];
    float* out = (float*)d_out;

    const int M = MROWS;
    char* ws = (char*)d_ws;
    const size_t SZ_H   = (size_t)M * 512 * 2;
    const size_t SZ_X2  = (size_t)M * 512 * 4;
    const size_t SZ_BIG = (size_t)M * 2048 * 2;
    u16*   h    = (u16*)ws;
    float* x2   = (float*)(ws + SZ_H);
    u16*   big  = (u16*)(ws + SZ_H + SZ_X2);
    u16*   qkv_wT  = (u16*)(ws + SZ_H + SZ_X2 + SZ_BIG);
    u16*   proj_wT = qkv_wT + 1536 * 512;
    u16*   w1T     = proj_wT + 512 * 512;
    u16*   w2T     = w1T + 2048 * 512;

    transpose_cast<<<(512 * 1536 + 255) / 256, 256, 0, stream>>>(qkv_w, qkv_wT, 512, 1536);
    transpose_cast<<<(512 * 512 + 255) / 256, 256, 0, stream>>>(proj_w, proj_wT, 512, 512);
    transpose_cast<<<(512 * 2048 + 255) / 256, 256, 0, stream>>>(mlp_w1, w1T, 512, 2048);
    transpose_cast<<<(2048 * 512 + 255) / 256, 256, 0, stream>>>(mlp_w2, w2T, 2048, 512);

    ln_kernel<<<M / 4, 256, 0, stream>>>(x, ln1_g, ln1_b, h);

    gemm_bt<EPI_BF16><<<(M / BM) * (1536 / BN), 256, 0, stream>>>(h, qkv_wT, qkv_b, nullptr, big, M, 1536, 512, 1536 / BN);

    attn_kernel<<<dim3(2048, 16), 64, 0, stream>>>(big, h);

    gemm_bt<EPI_RES_F32><<<(M / BM) * (512 / BN), 256, 0, stream>>>(h, proj_wT, proj_b, x, x2, M, 512, 512, 512 / BN);

    ln_kernel<<<M / 4, 256, 0, stream>>>(x2, ln2_g, ln2_b, h);

    gemm_bt<EPI_GELU_BF16><<<(M / BM) * (2048 / BN), 256, 0, stream>>>(h, w1T, mlp_b1, nullptr, big, M, 2048, 512, 2048 / BN);

    gemm_bt<EPI_RES_F32><<<(M / BM) * (512 / BN), 256, 0, stream>>>(big, w2T, mlp_b2, x2, out, M, 512, 2048, 512 / BN);
}

// Round 3
// 1677.478 us; speedup vs baseline: 1.2390x; 1.1460x over previous
//
#include <hip/hip_runtime.h>
#include <hip/hip_bf16.h>
#include <math.h>

typedef unsigned short u16;
typedef unsigned int u32;
typedef __bf16 bf16x8 __attribute__((ext_vector_type(8)));
typedef float f32x4 __attribute__((ext_vector_type(4)));

#define MROWS 100352   // 32 * 56 * 56
#define CDIM 512
#define SCALE_ATTN 0.17677669529663687f

__device__ __forceinline__ u16 f2bf(float f) {
    u32 u = __float_as_uint(f);
    u32 r = (u + 0x7fffu + ((u >> 16) & 1u)) >> 16;   // RNE
    return (u16)r;
}
__device__ __forceinline__ float bf2f(u16 h) {
    return __uint_as_float(((u32)h) << 16);
}

// ---------------- transpose + cast: fp32 W[K][N] -> bf16 WT[N][K] ----------------
__global__ void transpose_cast(const float* __restrict__ W, u16* __restrict__ WT, int K, int N) {
    int idx = blockIdx.x * 256 + threadIdx.x;
    if (idx >= K * N) return;
    int k = idx / N, n = idx % N;
    WT[(size_t)n * K + k] = f2bf(W[idx]);
}

// ---------------- LayerNorm fp32 -> bf16, one wave per row (C=512) ----------------
__global__ __launch_bounds__(256) void ln_kernel(const float* __restrict__ x, const float* __restrict__ g,
                                                 const float* __restrict__ bta, u16* __restrict__ out) {
    int row = blockIdx.x * 4 + (threadIdx.x >> 6);
    int lane = threadIdx.x & 63;
    const float* xr = x + (size_t)row * CDIM + lane * 8;
    float4 v0 = *(const float4*)xr;
    float4 v1 = *(const float4*)(xr + 4);
    float xv[8] = {v0.x, v0.y, v0.z, v0.w, v1.x, v1.y, v1.z, v1.w};
    float s = 0.f, ss = 0.f;
#pragma unroll
    for (int i = 0; i < 8; ++i) { s += xv[i]; ss += xv[i] * xv[i]; }
#pragma unroll
    for (int o = 1; o < 64; o <<= 1) { s += __shfl_xor(s, o); ss += __shfl_xor(ss, o); }
    float mu = s * (1.f / CDIM);
    float var = ss * (1.f / CDIM) - mu * mu;
    float rs = rsqrtf(var + 1e-6f);
    int c = lane * 8;
    u32 pk[4];
#pragma unroll
    for (int i = 0; i < 4; ++i) {
        float y0 = (xv[2 * i] - mu) * rs * g[c + 2 * i] + bta[c + 2 * i];
        float y1 = (xv[2 * i + 1] - mu) * rs * g[c + 2 * i + 1] + bta[c + 2 * i + 1];
        pk[i] = (u32)f2bf(y0) | ((u32)f2bf(y1) << 16);
    }
    uint4 ov; ov.x = pk[0]; ov.y = pk[1]; ov.z = pk[2]; ov.w = pk[3];
    *(uint4*)(out + (size_t)row * CDIM + c) = ov;
}

// ---------------- bf16 GEMM: C[M,N] = A[M,K] * BT[N,K]^T ----------------
// 128x128 tile, BK=64, 4 waves, double-buffered LDS (2-phase pipeline):
// STAGE(next) issued before compute(cur); end-of-iter __syncthreads (implicit
// vmcnt(0)+lgkmcnt(0) drain) makes next buffer ready and orders the
// read-before-overwrite. XOR swizzle (elem ^= (row&7)<<3) applied on the
// GLOBAL source column (linear LDS dest) + same XOR on the ds_read side.
#define BM 128
#define BN 128
#define BK 64

enum { EPI_BF16 = 0, EPI_GELU_BF16 = 1, EPI_RES_F32 = 2 };

__device__ __forceinline__ void gload_lds16(const void* g, void* l) {
    __builtin_amdgcn_global_load_lds(
        (const __attribute__((address_space(1))) u32*)g,
        (__attribute__((address_space(3))) u32*)l, 16, 0, 0);
}

template <int EPI>
__global__ __launch_bounds__(256) void gemm_bt(const u16* __restrict__ A, const u16* __restrict__ BT,
                                               const float* __restrict__ bias, const float* __restrict__ res,
                                               void* __restrict__ outp, int M, int N, int K, int nnb) {
    __shared__ __align__(16) u16 smem[2 * (BM * BK + BN * BK)];   // 64 KB

    const int t = threadIdx.x;
    const int lane = t & 63;
    const int w = t >> 6;
    const int wr = w >> 1, wc = w & 1;

    // XCD-bijective swizzle (nwg % 8 == 0 for all shapes here), then A-panel-major.
    const int nwg = gridDim.x;
    const int chunk = nwg >> 3;
    const int wg = (blockIdx.x & 7) * chunk + (blockIdx.x >> 3);
    const int m0 = (wg / nnb) * BM;
    const int n0 = (wg % nnb) * BN;

    f32x4 acc[4][4] = {};

    const int r15 = lane & 15;
    const int khalf = (lane >> 4) << 3;
    const int xorv = (r15 & 7) << 3;

    // per-thread staging coords (i-invariant parts)
    const int srow = t >> 3;                        // 0..31 within each 32-row group
    const int scol = (((t & 7) ^ (srow & 7)) << 3); // pre-swizzled global column
    const u16* Ag = A + (size_t)(m0 + srow) * K + scol;
    const u16* Bg = BT + (size_t)(n0 + srow) * K + scol;
    const int lbase0 = (w * 64) << 3;

    const int nt = K / BK;
    int cur = 0;

#define STAGE(buf, kt)                                                          \
    {                                                                           \
        u16* As_ = smem + (buf) * (BM * BK + BN * BK);                          \
        u16* Bs_ = As_ + BM * BK;                                               \
        _Pragma("unroll")                                                       \
        for (int i = 0; i < 4; ++i) {                                           \
            gload_lds16(Ag + (size_t)(i * 32) * K + (kt), &As_[i * 2048 + lbase0]); \
            gload_lds16(Bg + (size_t)(i * 32) * K + (kt), &Bs_[i * 2048 + lbase0]); \
        }                                                                       \
    }

    STAGE(0, 0);
    __syncthreads();

    for (int tix = 0; tix < nt; ++tix) {
        if (tix + 1 < nt) STAGE(cur ^ 1, (tix + 1) * BK);

        const u16* As = smem + cur * (BM * BK + BN * BK);
        const u16* Bs = As + BM * BK;
#pragma unroll
        for (int kk = 0; kk < BK; kk += 32) {
            bf16x8 af[4], bfr[4];
            int kof = (kk + khalf) ^ xorv;
#pragma unroll
            for (int mi = 0; mi < 4; ++mi)
                af[mi] = *(const bf16x8*)&As[(wr * 64 + mi * 16 + r15) * BK + kof];
#pragma unroll
            for (int ni = 0; ni < 4; ++ni)
                bfr[ni] = *(const bf16x8*)&Bs[(wc * 64 + ni * 16 + r15) * BK + kof];
#pragma unroll
            for (int mi = 0; mi < 4; ++mi)
#pragma unroll
                for (int ni = 0; ni < 4; ++ni)
                    acc[mi][ni] = __builtin_amdgcn_mfma_f32_16x16x32_bf16(af[mi], bfr[ni], acc[mi][ni], 0, 0, 0);
        }
        __syncthreads();   // vmcnt(0)+lgkmcnt(0) drain: next buffer ready, reads done before overwrite
        cur ^= 1;
    }
#undef STAGE

    // ---- coalesced epilogue: per-wave LDS staging (wave-private; no barriers needed) ----
    float* ep = (float*)smem + w * (16 * 72);
    const int lg = lane >> 4;
#pragma unroll
    for (int mi = 0; mi < 4; ++mi) {
#pragma unroll
        for (int ni = 0; ni < 4; ++ni)
#pragma unroll
            for (int j = 0; j < 4; ++j)
                ep[(lg * 4 + j) * 72 + ni * 16 + r15] = acc[mi][ni][j];
#pragma unroll
        for (int p = 0; p < 4; ++p) {
            int lr = p * 4 + lg;
            f32x4 v = *(f32x4*)&ep[lr * 72 + r15 * 4];
            int grow = m0 + wr * 64 + mi * 16 + lr;
            int gcol = n0 + wc * 64 + r15 * 4;
            float4 bv = *(const float4*)&bias[gcol];
            float o0 = v[0] + bv.x, o1 = v[1] + bv.y, o2 = v[2] + bv.z, o3 = v[3] + bv.w;
            if (EPI == EPI_GELU_BF16) {
                o0 = 0.5f * o0 * (1.f + erff(o0 * 0.70710678118654752f));
                o1 = 0.5f * o1 * (1.f + erff(o1 * 0.70710678118654752f));
                o2 = 0.5f * o2 * (1.f + erff(o2 * 0.70710678118654752f));
                o3 = 0.5f * o3 * (1.f + erff(o3 * 0.70710678118654752f));
            }
            if (EPI == EPI_RES_F32) {
                size_t off = (size_t)grow * N + gcol;
                float4 rv = *(const float4*)&res[off];
                float4 ov = make_float4(o0 + rv.x, o1 + rv.y, o2 + rv.z, o3 + rv.w);
                *(float4*)((float*)outp + off) = ov;
            } else {
                uint2 ov;
                ov.x = (u32)f2bf(o0) | ((u32)f2bf(o1) << 16);
                ov.y = (u32)f2bf(o2) | ((u32)f2bf(o3) << 16);
                *(uint2*)((u16*)outp + (size_t)grow * N + gcol) = ov;
            }
        }
    }
}

// ---------------- windowed attention: one wave per (window, head) ----------------
__global__ __launch_bounds__(64) void attn_kernel(const u16* __restrict__ qkv, u16* __restrict__ aout) {
    __shared__ float Ks[49 * 32];
    __shared__ float Vs[49 * 32];
    const int wdw = blockIdx.x;
    const int h = blockIdx.y;
    const int t = threadIdx.x;
    const int b = wdw >> 6, wy = (wdw >> 3) & 7, wx = wdw & 7;

    int row = 0;
    float q[32];
    if (t < 49) {
        int py = t / 7, px = t % 7;
        row = b * 3136 + (wy * 7 + py) * 56 + (wx * 7 + px);
        const u16* bp = qkv + (size_t)row * 1536 + h * 32;
#pragma unroll
        for (int i = 0; i < 4; ++i) {
            uint4 uq = *(const uint4*)(bp + i * 8);
            uint4 uk = *(const uint4*)(bp + 512 + i * 8);
            uint4 uv = *(const uint4*)(bp + 1024 + i * 8);
            u32 qa[4] = {uq.x, uq.y, uq.z, uq.w};
            u32 ka[4] = {uk.x, uk.y, uk.z, uk.w};
            u32 va[4] = {uv.x, uv.y, uv.z, uv.w};
#pragma unroll
            for (int j = 0; j < 4; ++j) {
                q[i * 8 + 2 * j] = bf2f((u16)(qa[j] & 0xffffu));
                q[i * 8 + 2 * j + 1] = bf2f((u16)(qa[j] >> 16));
                Ks[t * 32 + i * 8 + 2 * j] = bf2f((u16)(ka[j] & 0xffffu));
                Ks[t * 32 + i * 8 + 2 * j + 1] = bf2f((u16)(ka[j] >> 16));
                Vs[t * 32 + i * 8 + 2 * j] = bf2f((u16)(va[j] & 0xffffu));
                Vs[t * 32 + i * 8 + 2 * j + 1] = bf2f((u16)(va[j] >> 16));
            }
        }
    }
    __syncthreads();
    if (t >= 49) return;

    float s[49];
    float mx = -1e30f;
    for (int m = 0; m < 49; ++m) {
        float acc = 0.f;
#pragma unroll
        for (int d = 0; d < 32; ++d) acc += q[d] * Ks[m * 32 + d];
        acc *= SCALE_ATTN;
        s[m] = acc;
        mx = fmaxf(mx, acc);
    }
    float sum = 0.f;
    for (int m = 0; m < 49; ++m) { float e = __expf(s[m] - mx); s[m] = e; sum += e; }
    float inv = 1.f / sum;
    float o[32];
#pragma unroll
    for (int d = 0; d < 32; ++d) o[d] = 0.f;
    for (int m = 0; m < 49; ++m) {
        float p = s[m] * inv;
#pragma unroll
        for (int d = 0; d < 32; ++d) o[d] += p * Vs[m * 32 + d];
    }
    u16* op = aout + (size_t)row * 512 + h * 32;
#pragma unroll
    for (int i = 0; i < 4; ++i) {
        uint4 ov;
        ov.x = (u32)f2bf(o[i * 8 + 0]) | ((u32)f2bf(o[i * 8 + 1]) << 16);
        ov.y = (u32)f2bf(o[i * 8 + 2]) | ((u32)f2bf(o[i * 8 + 3]) << 16);
        ov.z = (u32)f2bf(o[i * 8 + 4]) | ((u32)f2bf(o[i * 8 + 5]) << 16);
        ov.w = (u32)f2bf(o[i * 8 + 6]) | ((u32)f2bf(o[i * 8 + 7]) << 16);
        *(uint4*)(op + i * 8) = ov;
    }
}

// ---------------- launch ----------------
extern "C" void kernel_launch(void* const* d_in, const int* in_sizes, int n_in,
                              void* d_out, int out_size, void* d_ws, size_t ws_size,
                              hipStream_t stream) {
    (void)in_sizes; (void)n_in; (void)out_size; (void)ws_size;
    const float* x      = (const float*)d_in[0];
    const float* ln1_g  = (const float*)d_in[1];
    const float* ln1_b  = (const float*)d_in[2];
    const float* qkv_w  = (const float*)d_in[3];
    const float* qkv_b  = (const float*)d_in[4];
    const float* proj_w = (const float*)d_in[5];
    const float* proj_b = (const float*)d_in[6];
    const float* ln2_g  = (const float*)d_in[7];
    const float* ln2_b  = (const float*)d_in[8];
    const float* mlp_w1 = (const float*)d_in[9];
    const float* mlp_b1 = (const float*)d_in[10];
    const float* mlp_w2 = (const float*)d_in[11];
    const float* mlp_b2 = (const float*)d_in[12];
    float* out = (float*)d_out;

    const int M = MROWS;
    char* ws = (char*)d_ws;
    const size_t SZ_H   = (size_t)M * 512 * 2;
    const size_t SZ_X2  = (size_t)M * 512 * 4;
    const size_t SZ_BIG = (size_t)M * 2048 * 2;
    u16*   h    = (u16*)ws;
    float* x2   = (float*)(ws + SZ_H);
    u16*   big  = (u16*)(ws + SZ_H + SZ_X2);
    u16*   qkv_wT  = (u16*)(ws + SZ_H + SZ_X2 + SZ_BIG);
    u16*   proj_wT = qkv_wT + 1536 * 512;
    u16*   w1T     = proj_wT + 512 * 512;
    u16*   w2T     = w1T + 2048 * 512;

    transpose_cast<<<(512 * 1536 + 255) / 256, 256, 0, stream>>>(qkv_w, qkv_wT, 512, 1536);
    transpose_cast<<<(512 * 512 + 255) / 256, 256, 0, stream>>>(proj_w, proj_wT, 512, 512);
    transpose_cast<<<(512 * 2048 + 255) / 256, 256, 0, stream>>>(mlp_w1, w1T, 512, 2048);
    transpose_cast<<<(2048 * 512 + 255) / 256, 256, 0, stream>>>(mlp_w2, w2T, 2048, 512);

    ln_kernel<<<M / 4, 256, 0, stream>>>(x, ln1_g, ln1_b, h);

    gemm_bt<EPI_BF16><<<(M / BM) * (1536 / BN), 256, 0, stream>>>(h, qkv_wT, qkv_b, nullptr, big, M, 1536, 512, 1536 / BN);

    attn_kernel<<<dim3(2048, 16), 64, 0, stream>>>(big, h);

    gemm_bt<EPI_RES_F32><<<(M / BM) * (512 / BN), 256, 0, stream>>>(h, proj_wT, proj_b, x, x2, M, 512, 512, 512 / BN);

    ln_kernel<<<M / 4, 256, 0, stream>>>(x2, ln2_g, ln2_b, h);

    gemm_bt<EPI_GELU_BF16><<<(M / BM) * (2048 / BN), 256, 0, stream>>>(h, w1T, mlp_b1, nullptr, big, M, 2048, 512, 2048 / BN);

    gemm_bt<EPI_RES_F32><<<(M / BM) * (512 / BN), 256, 0, stream>>>(big, w2T, mlp_b2, x2, out, M, 512, 2048, 512 / BN);
}

// Round 4
// 1619.161 us; speedup vs baseline: 1.2836x; 1.0360x over previous
//
#include <hip/hip_runtime.h>
#include <hip/hip_bf16.h>
#include <math.h>

typedef unsigned short u16;
typedef unsigned int u32;
typedef __bf16 bf16x8 __attribute__((ext_vector_type(8)));
typedef float f32x4 __attribute__((ext_vector_type(4)));

#define MROWS 100352   // 32 * 56 * 56
#define CDIM 512
#define SCALE_ATTN 0.17677669529663687f

__device__ __forceinline__ u16 f2bf(float f) {
    u32 u = __float_as_uint(f);
    u32 r = (u + 0x7fffu + ((u >> 16) & 1u)) >> 16;   // RNE
    return (u16)r;
}
__device__ __forceinline__ float bf2f(u16 h) {
    return __uint_as_float(((u32)h) << 16);
}

// ---------------- transpose + cast: fp32 W[K][N] -> bf16 WT[N][K] ----------------
__global__ void transpose_cast(const float* __restrict__ W, u16* __restrict__ WT, int K, int N) {
    int idx = blockIdx.x * 256 + threadIdx.x;
    if (idx >= K * N) return;
    int k = idx / N, n = idx % N;
    WT[(size_t)n * K + k] = f2bf(W[idx]);
}

// ---------------- LayerNorm fp32 -> bf16, one wave per row (C=512) ----------------
__global__ __launch_bounds__(256) void ln_kernel(const float* __restrict__ x, const float* __restrict__ g,
                                                 const float* __restrict__ bta, u16* __restrict__ out) {
    int row = blockIdx.x * 4 + (threadIdx.x >> 6);
    int lane = threadIdx.x & 63;
    const float* xr = x + (size_t)row * CDIM + lane * 8;
    float4 v0 = *(const float4*)xr;
    float4 v1 = *(const float4*)(xr + 4);
    float xv[8] = {v0.x, v0.y, v0.z, v0.w, v1.x, v1.y, v1.z, v1.w};
    float s = 0.f, ss = 0.f;
#pragma unroll
    for (int i = 0; i < 8; ++i) { s += xv[i]; ss += xv[i] * xv[i]; }
#pragma unroll
    for (int o = 1; o < 64; o <<= 1) { s += __shfl_xor(s, o); ss += __shfl_xor(ss, o); }
    float mu = s * (1.f / CDIM);
    float var = ss * (1.f / CDIM) - mu * mu;
    float rs = rsqrtf(var + 1e-6f);
    int c = lane * 8;
    u32 pk[4];
#pragma unroll
    for (int i = 0; i < 4; ++i) {
        float y0 = (xv[2 * i] - mu) * rs * g[c + 2 * i] + bta[c + 2 * i];
        float y1 = (xv[2 * i + 1] - mu) * rs * g[c + 2 * i + 1] + bta[c + 2 * i + 1];
        pk[i] = (u32)f2bf(y0) | ((u32)f2bf(y1) << 16);
    }
    uint4 ov; ov.x = pk[0]; ov.y = pk[1]; ov.z = pk[2]; ov.w = pk[3];
    *(uint4*)(out + (size_t)row * CDIM + c) = ov;
}

// ---------------- bf16 GEMM: C[M,N] = A[M,K] * BT[N,K]^T ----------------
// 256x128 tile, BK=64, 8 waves (4 along M x 2 along N), 3-buffer LDS with
// counted-vmcnt pipeline (2-tile prefetch distance, vmcnt never drained to 0
// in steady state). XOR swizzle via pre-swizzled global source column
// (linear LDS dest for global_load_lds) + same XOR on ds_read side.
#define BM 256
#define BN 128
#define BK 64
#define BUF_ELEMS (BM * BK + BN * BK)   // 24576 u16 = 48KB

enum { EPI_BF16 = 0, EPI_GELU_BF16 = 1, EPI_RES_F32 = 2 };

__device__ __forceinline__ void gload_lds16(const void* g, void* l) {
    __builtin_amdgcn_global_load_lds(
        (const __attribute__((address_space(1))) u32*)g,
        (__attribute__((address_space(3))) u32*)l, 16, 0, 0);
}

#define WAITVM6() asm volatile("s_waitcnt vmcnt(6)" ::: "memory")
#define WAITVM0() asm volatile("s_waitcnt vmcnt(0)" ::: "memory")
#define BARRIER() __builtin_amdgcn_s_barrier()

__device__ __forceinline__ float gelu_tanh(float x) {
    // exact-GELU tanh approximation; |err| < ~3e-3, far under bf16 floor here.
    float y = 0.7978845608028654f * (x + 0.044715f * x * x * x);
    y = fmaxf(y, -20.f);                 // avoid exp overflow for very negative x
    float u = __expf(-2.f * y);
    float th = (1.f - u) / (1.f + u);
    return 0.5f * x * (1.f + th);
}

template <int EPI>
__global__ __launch_bounds__(512) void gemm_bt(const u16* __restrict__ A, const u16* __restrict__ BT,
                                               const float* __restrict__ bias, const float* __restrict__ res,
                                               void* __restrict__ outp, int M, int N, int K, int nnb) {
    __shared__ __align__(16) u16 smem[3 * BUF_ELEMS];   // 144 KB

    const int t = threadIdx.x;
    const int lane = t & 63;
    const int w = t >> 6;
    const int wr = w >> 1, wc = w & 1;   // 4 waves along M, 2 along N

    // XCD-bijective swizzle (grid % 8 == 0 for all shapes here), A-panel-major.
    const int nwg = gridDim.x;
    const int chunk = nwg >> 3;
    const int wg = (blockIdx.x & 7) * chunk + (blockIdx.x >> 3);
    const int m0 = (wg / nnb) * BM;
    const int n0 = (wg % nnb) * BN;

    f32x4 acc[4][4] = {};

    const int r15 = lane & 15;
    const int khalf = (lane >> 4) << 3;
    const int xorv = (r15 & 7) << 3;

    // staging coords: 512 threads, 8 threads/row, 64 rows per issue
    const int srow = t >> 3;                        // 0..63
    const int scol = (((t & 7) ^ (srow & 7)) << 3); // pre-swizzled global column
    const u16* Ag = A + (size_t)(m0 + srow) * K + scol;
    const u16* Bg = BT + (size_t)(n0 + srow) * K + scol;
    const int ldst = t * 8;                          // linear per-thread LDS elem offset

    const int nt = K / BK;

#define ISSUE(buf_, tile_)                                                          \
    {                                                                               \
        u16* dst = smem + (buf_) * BUF_ELEMS;                                       \
        const int kt_ = (tile_) * BK;                                               \
        _Pragma("unroll")                                                           \
        for (int i = 0; i < 4; ++i)                                                 \
            gload_lds16(Ag + (size_t)(i * 64) * K + kt_, &dst[i * 4096 + ldst]);    \
        _Pragma("unroll")                                                           \
        for (int i = 0; i < 2; ++i)                                                 \
            gload_lds16(Bg + (size_t)(i * 64) * K + kt_, &dst[BM * BK + i * 4096 + ldst]); \
    }

    // prologue: tiles 0,1 in flight; wait for tile 0 (6 newest = tile 1 allowed out)
    ISSUE(0, 0);
    ISSUE(1, 1);
    WAITVM6();
    BARRIER();

    int bufc = 0;
    for (int tt = 0; tt < nt; ++tt) {
        int bn2 = bufc + 2; if (bn2 >= 3) bn2 -= 3;
        if (tt + 2 < nt) ISSUE(bn2, tt + 2);   // into buffer not referenced this or next iter

        const u16* As = smem + bufc * BUF_ELEMS;
        const u16* Bs = As + BM * BK;
#pragma unroll
        for (int kk = 0; kk < BK; kk += 32) {
            bf16x8 af[4], bfr[4];
            int kof = (kk + khalf) ^ xorv;
#pragma unroll
            for (int mi = 0; mi < 4; ++mi)
                af[mi] = *(const bf16x8*)&As[(wr * 64 + mi * 16 + r15) * BK + kof];
#pragma unroll
            for (int ni = 0; ni < 4; ++ni)
                bfr[ni] = *(const bf16x8*)&Bs[(wc * 64 + ni * 16 + r15) * BK + kof];
#pragma unroll
            for (int mi = 0; mi < 4; ++mi)
#pragma unroll
                for (int ni = 0; ni < 4; ++ni)
                    acc[mi][ni] = __builtin_amdgcn_mfma_f32_16x16x32_bf16(af[mi], bfr[ni], acc[mi][ni], 0, 0, 0);
        }

        if (tt + 1 < nt) {
            if (tt + 2 < nt) WAITVM6();   // tile t+1 resident (its 6 loads no longer among newest 6)
            else WAITVM0();               // last prefetched tile: drain (issued long ago, cheap)
        }
        BARRIER();                        // all waves: next tile visible, this tile's reads done
        bufc = (bufc + 1 == 3) ? 0 : bufc + 1;
    }
#undef ISSUE
    __builtin_amdgcn_sched_barrier(0);    // pin: no LDS reads sink past here (epilogue reuses smem)

    // ---- coalesced epilogue: per-wave LDS staging (wave-private; 76-float pad) ----
    float* ep = (float*)smem + w * (16 * 76);
    const int lg = lane >> 4;
#pragma unroll
    for (int mi = 0; mi < 4; ++mi) {
#pragma unroll
        for (int ni = 0; ni < 4; ++ni)
#pragma unroll
            for (int j = 0; j < 4; ++j)
                ep[(lg * 4 + j) * 76 + ni * 16 + r15] = acc[mi][ni][j];
#pragma unroll
        for (int p = 0; p < 4; ++p) {
            int lr = p * 4 + lg;
            f32x4 v = *(f32x4*)&ep[lr * 76 + r15 * 4];
            int grow = m0 + wr * 64 + mi * 16 + lr;
            int gcol = n0 + wc * 64 + r15 * 4;
            float4 bv = *(const float4*)&bias[gcol];
            float o0 = v[0] + bv.x, o1 = v[1] + bv.y, o2 = v[2] + bv.z, o3 = v[3] + bv.w;
            if (EPI == EPI_GELU_BF16) {
                o0 = gelu_tanh(o0); o1 = gelu_tanh(o1); o2 = gelu_tanh(o2); o3 = gelu_tanh(o3);
            }
            if (EPI == EPI_RES_F32) {
                size_t off = (size_t)grow * N + gcol;
                float4 rv = *(const float4*)&res[off];
                float4 ov = make_float4(o0 + rv.x, o1 + rv.y, o2 + rv.z, o3 + rv.w);
                *(float4*)((float*)outp + off) = ov;
            } else {
                uint2 ov;
                ov.x = (u32)f2bf(o0) | ((u32)f2bf(o1) << 16);
                ov.y = (u32)f2bf(o2) | ((u32)f2bf(o3) << 16);
                *(uint2*)((u16*)outp + (size_t)grow * N + gcol) = ov;
            }
        }
    }
}

// ---------------- windowed attention: one wave per (window, head) ----------------
__global__ __launch_bounds__(64) void attn_kernel(const u16* __restrict__ qkv, u16* __restrict__ aout) {
    __shared__ float Ks[49 * 32];
    __shared__ float Vs[49 * 32];
    const int wdw = blockIdx.x;
    const int h = blockIdx.y;
    const int t = threadIdx.x;
    const int b = wdw >> 6, wy = (wdw >> 3) & 7, wx = wdw & 7;

    int row = 0;
    float q[32];
    if (t < 49) {
        int py = t / 7, px = t % 7;
        row = b * 3136 + (wy * 7 + py) * 56 + (wx * 7 + px);
        const u16* bp = qkv + (size_t)row * 1536 + h * 32;
#pragma unroll
        for (int i = 0; i < 4; ++i) {
            uint4 uq = *(const uint4*)(bp + i * 8);
            uint4 uk = *(const uint4*)(bp + 512 + i * 8);
            uint4 uv = *(const uint4*)(bp + 1024 + i * 8);
            u32 qa[4] = {uq.x, uq.y, uq.z, uq.w};
            u32 ka[4] = {uk.x, uk.y, uk.z, uk.w};
            u32 va[4] = {uv.x, uv.y, uv.z, uv.w};
#pragma unroll
            for (int j = 0; j < 4; ++j) {
                q[i * 8 + 2 * j] = bf2f((u16)(qa[j] & 0xffffu));
                q[i * 8 + 2 * j + 1] = bf2f((u16)(qa[j] >> 16));
                Ks[t * 32 + i * 8 + 2 * j] = bf2f((u16)(ka[j] & 0xffffu));
                Ks[t * 32 + i * 8 + 2 * j + 1] = bf2f((u16)(ka[j] >> 16));
                Vs[t * 32 + i * 8 + 2 * j] = bf2f((u16)(va[j] & 0xffffu));
                Vs[t * 32 + i * 8 + 2 * j + 1] = bf2f((u16)(va[j] >> 16));
            }
        }
    }
    __syncthreads();
    if (t >= 49) return;

    float s[49];
    float mx = -1e30f;
    for (int m = 0; m < 49; ++m) {
        float acc = 0.f;
#pragma unroll
        for (int d = 0; d < 32; ++d) acc += q[d] * Ks[m * 32 + d];
        acc *= SCALE_ATTN;
        s[m] = acc;
        mx = fmaxf(mx, acc);
    }
    float sum = 0.f;
    for (int m = 0; m < 49; ++m) { float e = __expf(s[m] - mx); s[m] = e; sum += e; }
    float inv = 1.f / sum;
    float o[32];
#pragma unroll
    for (int d = 0; d < 32; ++d) o[d] = 0.f;
    for (int m = 0; m < 49; ++m) {
        float p = s[m] * inv;
#pragma unroll
        for (int d = 0; d < 32; ++d) o[d] += p * Vs[m * 32 + d];
    }
    u16* op = aout + (size_t)row * 512 + h * 32;
#pragma unroll
    for (int i = 0; i < 4; ++i) {
        uint4 ov;
        ov.x = (u32)f2bf(o[i * 8 + 0]) | ((u32)f2bf(o[i * 8 + 1]) << 16);
        ov.y = (u32)f2bf(o[i * 8 + 2]) | ((u32)f2bf(o[i * 8 + 3]) << 16);
        ov.z = (u32)f2bf(o[i * 8 + 4]) | ((u32)f2bf(o[i * 8 + 5]) << 16);
        ov.w = (u32)f2bf(o[i * 8 + 6]) | ((u32)f2bf(o[i * 8 + 7]) << 16);
        *(uint4*)(op + i * 8) = ov;
    }
}

// ---------------- launch ----------------
extern "C" void kernel_launch(void* const* d_in, const int* in_sizes, int n_in,
                              void* d_out, int out_size, void* d_ws, size_t ws_size,
                              hipStream_t stream) {
    (void)in_sizes; (void)n_in; (void)out_size; (void)ws_size;
    const float* x      = (const float*)d_in[0];
    const float* ln1_g  = (const float*)d_in[1];
    const float* ln1_b  = (const float*)d_in[2];
    const float* qkv_w  = (const float*)d_in[3];
    const float* qkv_b  = (const float*)d_in[4];
    const float* proj_w = (const float*)d_in[5];
    const float* proj_b = (const float*)d_in[6];
    const float* ln2_g  = (const float*)d_in[7];
    const float* ln2_b  = (const float*)d_in[8];
    const float* mlp_w1 = (const float*)d_in[9];
    const float* mlp_b1 = (const float*)d_in[10];
    const float* mlp_w2 = (const float*)d_in[11];
    const float* mlp_b2 = (const float*)d_in[12];
    float* out = (float*)d_out;

    const int M = MROWS;
    char* ws = (char*)d_ws;
    const size_t SZ_H   = (size_t)M * 512 * 2;
    const size_t SZ_X2  = (size_t)M * 512 * 4;
    const size_t SZ_BIG = (size_t)M * 2048 * 2;
    u16*   h    = (u16*)ws;
    float* x2   = (float*)(ws + SZ_H);
    u16*   big  = (u16*)(ws + SZ_H + SZ_X2);
    u16*   qkv_wT  = (u16*)(ws + SZ_H + SZ_X2 + SZ_BIG);
    u16*   proj_wT = qkv_wT + 1536 * 512;
    u16*   w1T     = proj_wT + 512 * 512;
    u16*   w2T     = w1T + 2048 * 512;

    transpose_cast<<<(512 * 1536 + 255) / 256, 256, 0, stream>>>(qkv_w, qkv_wT, 512, 1536);
    transpose_cast<<<(512 * 512 + 255) / 256, 256, 0, stream>>>(proj_w, proj_wT, 512, 512);
    transpose_cast<<<(512 * 2048 + 255) / 256, 256, 0, stream>>>(mlp_w1, w1T, 512, 2048);
    transpose_cast<<<(2048 * 512 + 255) / 256, 256, 0, stream>>>(mlp_w2, w2T, 2048, 512);

    ln_kernel<<<M / 4, 256, 0, stream>>>(x, ln1_g, ln1_b, h);

    gemm_bt<EPI_BF16><<<(M / BM) * (1536 / BN), 512, 0, stream>>>(h, qkv_wT, qkv_b, nullptr, big, M, 1536, 512, 1536 / BN);

    attn_kernel<<<dim3(2048, 16), 64, 0, stream>>>(big, h);

    gemm_bt<EPI_RES_F32><<<(M / BM) * (512 / BN), 512, 0, stream>>>(h, proj_wT, proj_b, x, x2, M, 512, 512, 512 / BN);

    ln_kernel<<<M / 4, 256, 0, stream>>>(x2, ln2_g, ln2_b, h);

    gemm_bt<EPI_GELU_BF16><<<(M / BM) * (2048 / BN), 512, 0, stream>>>(h, w1T, mlp_b1, nullptr, big, M, 2048, 512, 2048 / BN);

    gemm_bt<EPI_RES_F32><<<(M / BM) * (512 / BN), 512, 0, stream>>>(big, w2T, mlp_b2, x2, out, M, 512, 2048, 512 / BN);
}

// Round 5
// 1505.074 us; speedup vs baseline: 1.3809x; 1.0758x over previous
//
#include <hip/hip_runtime.h>
#include <hip/hip_bf16.h>
#include <math.h>

typedef unsigned short u16;
typedef unsigned int u32;
typedef __bf16 bf16x8 __attribute__((ext_vector_type(8)));
typedef float f32x4 __attribute__((ext_vector_type(4)));

#define MROWS 100352   // 32 * 56 * 56
#define CDIM 512
#define SCALE_ATTN 0.17677669529663687f

__device__ __forceinline__ u16 f2bf(float f) {
    u32 u = __float_as_uint(f);
    u32 r = (u + 0x7fffu + ((u >> 16) & 1u)) >> 16;   // RNE
    return (u16)r;
}
__device__ __forceinline__ float bf2f(u16 h) {
    return __uint_as_float(((u32)h) << 16);
}

// ---------------- transpose + cast: fp32 W[K][N] -> bf16 WT[N][K] ----------------
__global__ void transpose_cast(const float* __restrict__ W, u16* __restrict__ WT, int K, int N) {
    int idx = blockIdx.x * 256 + threadIdx.x;
    if (idx >= K * N) return;
    int k = idx / N, n = idx % N;
    WT[(size_t)n * K + k] = f2bf(W[idx]);
}

// ---------------- LayerNorm fp32 -> bf16, one wave per row (C=512) ----------------
__global__ __launch_bounds__(256) void ln_kernel(const float* __restrict__ x, const float* __restrict__ g,
                                                 const float* __restrict__ bta, u16* __restrict__ out) {
    int row = blockIdx.x * 4 + (threadIdx.x >> 6);
    int lane = threadIdx.x & 63;
    const float* xr = x + (size_t)row * CDIM + lane * 8;
    float4 v0 = *(const float4*)xr;
    float4 v1 = *(const float4*)(xr + 4);
    float xv[8] = {v0.x, v0.y, v0.z, v0.w, v1.x, v1.y, v1.z, v1.w};
    float s = 0.f, ss = 0.f;
#pragma unroll
    for (int i = 0; i < 8; ++i) { s += xv[i]; ss += xv[i] * xv[i]; }
#pragma unroll
    for (int o = 1; o < 64; o <<= 1) { s += __shfl_xor(s, o); ss += __shfl_xor(ss, o); }
    float mu = s * (1.f / CDIM);
    float var = ss * (1.f / CDIM) - mu * mu;
    float rs = rsqrtf(var + 1e-6f);
    int c = lane * 8;
    u32 pk[4];
#pragma unroll
    for (int i = 0; i < 4; ++i) {
        float y0 = (xv[2 * i] - mu) * rs * g[c + 2 * i] + bta[c + 2 * i];
        float y1 = (xv[2 * i + 1] - mu) * rs * g[c + 2 * i + 1] + bta[c + 2 * i + 1];
        pk[i] = (u32)f2bf(y0) | ((u32)f2bf(y1) << 16);
    }
    uint4 ov; ov.x = pk[0]; ov.y = pk[1]; ov.z = pk[2]; ov.w = pk[3];
    *(uint4*)(out + (size_t)row * CDIM + c) = ov;
}

// ---------------- bf16 GEMM, 8-phase 256x256 template: C = A * BT^T ----------------
// 256x256 tile, BK=64, 8 waves (2 along M x 4 along N), per-wave 128x64 output.
// LDS 128KB: 2 dbuf x (A 256x64 + B 256x64). 4 phases per K-tile, 16 MFMA each,
// B-frags for the whole tile read at phase 0 (held in regs), A-frags 4 per phase.
// Tile t+1's 4 half-tiles staged one per phase during tile t (into dbuf holding
// dead tile t-1). vmcnt(2) + barrier at each tile's phase 0 covers its data;
// never drained to 0 mid-loop. XOR swizzle via pre-swizzled global source.
#define BM 256
#define BN 256
#define BK 64

enum { EPI_BF16 = 0, EPI_GELU_BF16 = 1, EPI_RES_F32 = 2 };

__device__ __forceinline__ void gload_lds16(const void* g, void* l) {
    __builtin_amdgcn_global_load_lds(
        (const __attribute__((address_space(1))) u32*)g,
        (__attribute__((address_space(3))) u32*)l, 16, 0, 0);
}

#define WAITVM2() asm volatile("s_waitcnt vmcnt(2)" ::: "memory")
#define WAITVM0() asm volatile("s_waitcnt vmcnt(0)" ::: "memory")
#define BARRIER() __builtin_amdgcn_s_barrier()
#define SCHEDBAR() __builtin_amdgcn_sched_barrier(0)

__device__ __forceinline__ float gelu_tanh(float x) {
    float y = 0.7978845608028654f * (x + 0.044715f * x * x * x);
    y = fmaxf(y, -20.f);
    float u = __expf(-2.f * y);
    float th = (1.f - u) / (1.f + u);
    return 0.5f * x * (1.f + th);
}

template <int EPI>
__global__ __launch_bounds__(512, 2) void gemm_bt(const u16* __restrict__ A, const u16* __restrict__ BT,
                                                  const float* __restrict__ bias, const float* __restrict__ res,
                                                  void* __restrict__ outp, int M, int N, int K, int nnb) {
    __shared__ __align__(16) u16 smem[65536];   // 128 KB: A0 A1 | B0 B1 (16384 u16 each)

    const int t = threadIdx.x;
    const int lane = t & 63;
    const int w = t >> 6;
    const int wm = w >> 2, wn = w & 3;   // 2 waves along M, 4 along N

    // XCD-bijective swizzle (grid % 8 == 0 for all shapes here), A-panel-major.
    const int nwg = gridDim.x;
    const int chunk = nwg >> 3;
    const int wg = (blockIdx.x & 7) * chunk + (blockIdx.x >> 3);
    const int m0 = (wg / nnb) * BM;
    const int n0 = (wg % nnb) * BN;

    f32x4 acc[8][4] = {};

    const int r15 = lane & 15;
    const int khalf = (lane >> 4) << 3;
    const int xorv = (r15 & 7) << 3;

    // staging coords: 512 threads, 8 threads/row, 64 rows per gload line
    const int srow = t >> 3;                        // 0..63
    const int scol = (((t & 7) ^ (srow & 7)) << 3); // pre-swizzled global column
    const u16* Ag = A + (size_t)(m0 + srow) * K + scol;
    const u16* Bg = BT + (size_t)(n0 + srow) * K + scol;

    const int nt = K / BK;

    // stage half h_ (0,1 = A rows 0-127/128-255; 2,3 = B rows 0-127/128-255)
    // of K-tile tile_ into dbuf dd_
#define STAGE_HALF(h_, tile_, dd_)                                                   \
    {                                                                                \
        const int kt_ = (tile_) * BK;                                                \
        u16* dst_ = smem + ((h_) < 2 ? 0 : 32768) + (dd_) * 16384 + ((h_) & 1) * 8192; \
        const u16* src_ = (((h_) < 2) ? Ag : Bg) + (size_t)(((h_) & 1) * 128) * K + kt_; \
        gload_lds16(src_, &dst_[t * 8]);                                             \
        gload_lds16(src_ + (size_t)64 * K, &dst_[4096 + t * 8]);                     \
    }

    // prologue: stage all 4 halves of tile 0 into dbuf 0
    STAGE_HALF(0, 0, 0); STAGE_HALF(1, 0, 0); STAGE_HALF(2, 0, 0); STAGE_HALF(3, 0, 0);

    for (int tt = 0; tt < nt; ++tt) {
        const int d = tt & 1;
        const u16* As = smem + d * 16384;
        const u16* Bs = smem + 32768 + d * 16384;
        bf16x8 bfr[4][2];   // whole-tile B fragments, read at phase 0, live all phases

#pragma unroll
        for (int p = 0; p < 4; ++p) {
            // stage half p of tile tt+1 into the other dbuf (holds dead tile tt-1)
            if (tt + 1 < nt) STAGE_HALF(p, tt + 1, d ^ 1);

            if (p == 0) {
                // cover tile tt's 8 loads; the 2 just-issued (tile tt+1 half 0) stay in flight
                if (tt + 1 < nt) WAITVM2(); else WAITVM0();
                BARRIER();      // all waves' vmcnt done -> tile tt globally visible in LDS
                SCHEDBAR();     // pin: no ds_read hoists above this point
#pragma unroll
                for (int ni = 0; ni < 4; ++ni)
#pragma unroll
                    for (int kk = 0; kk < 2; ++kk)
                        bfr[ni][kk] = *(const bf16x8*)&Bs[(wn * 64 + ni * 16 + r15) * BK + ((kk * 32 + khalf) ^ xorv)];
            }

            bf16x8 af[2][2];
#pragma unroll
            for (int q = 0; q < 2; ++q)
#pragma unroll
                for (int kk = 0; kk < 2; ++kk)
                    af[q][kk] = *(const bf16x8*)&As[(wm * 128 + (2 * p + q) * 16 + r15) * BK + ((kk * 32 + khalf) ^ xorv)];

            if (p != 0) { BARRIER(); SCHEDBAR(); }   // pre-MFMA phase alignment

            __builtin_amdgcn_s_setprio(1);
#pragma unroll
            for (int kk = 0; kk < 2; ++kk)
#pragma unroll
                for (int q = 0; q < 2; ++q)
#pragma unroll
                    for (int ni = 0; ni < 4; ++ni)
                        acc[2 * p + q][ni] = __builtin_amdgcn_mfma_f32_16x16x32_bf16(af[q][kk], bfr[ni][kk], acc[2 * p + q][ni], 0, 0, 0);
            __builtin_amdgcn_s_setprio(0);

            BARRIER();          // closing: phase p reads fully consumed before next stages
            SCHEDBAR();
        }
    }
#undef STAGE_HALF

    // ---- coalesced epilogue: per-wave LDS staging (wave-private, 76-float pad) ----
    float* ep = (float*)smem + w * (16 * 76);
    const int lg = lane >> 4;
#pragma unroll
    for (int mi = 0; mi < 8; ++mi) {
#pragma unroll
        for (int ni = 0; ni < 4; ++ni)
#pragma unroll
            for (int j = 0; j < 4; ++j)
                ep[(lg * 4 + j) * 76 + ni * 16 + r15] = acc[mi][ni][j];
#pragma unroll
        for (int p = 0; p < 4; ++p) {
            int lr = p * 4 + lg;
            f32x4 v = *(f32x4*)&ep[lr * 76 + r15 * 4];
            int grow = m0 + wm * 128 + mi * 16 + lr;
            int gcol = n0 + wn * 64 + r15 * 4;
            float4 bv = *(const float4*)&bias[gcol];
            float o0 = v[0] + bv.x, o1 = v[1] + bv.y, o2 = v[2] + bv.z, o3 = v[3] + bv.w;
            if (EPI == EPI_GELU_BF16) {
                o0 = gelu_tanh(o0); o1 = gelu_tanh(o1); o2 = gelu_tanh(o2); o3 = gelu_tanh(o3);
            }
            if (EPI == EPI_RES_F32) {
                size_t off = (size_t)grow * N + gcol;
                float4 rv = *(const float4*)&res[off];
                float4 ov = make_float4(o0 + rv.x, o1 + rv.y, o2 + rv.z, o3 + rv.w);
                *(float4*)((float*)outp + off) = ov;
            } else {
                uint2 ov;
                ov.x = (u32)f2bf(o0) | ((u32)f2bf(o1) << 16);
                ov.y = (u32)f2bf(o2) | ((u32)f2bf(o3) << 16);
                *(uint2*)((u16*)outp + (size_t)grow * N + gcol) = ov;
            }
        }
    }
}

// ---------------- windowed attention: one wave per (window, head) ----------------
__global__ __launch_bounds__(64) void attn_kernel(const u16* __restrict__ qkv, u16* __restrict__ aout) {
    __shared__ float Ks[49 * 32];
    __shared__ float Vs[49 * 32];
    const int wdw = blockIdx.x;
    const int h = blockIdx.y;
    const int t = threadIdx.x;
    const int b = wdw >> 6, wy = (wdw >> 3) & 7, wx = wdw & 7;

    int row = 0;
    float q[32];
    if (t < 49) {
        int py = t / 7, px = t % 7;
        row = b * 3136 + (wy * 7 + py) * 56 + (wx * 7 + px);
        const u16* bp = qkv + (size_t)row * 1536 + h * 32;
#pragma unroll
        for (int i = 0; i < 4; ++i) {
            uint4 uq = *(const uint4*)(bp + i * 8);
            uint4 uk = *(const uint4*)(bp + 512 + i * 8);
            uint4 uv = *(const uint4*)(bp + 1024 + i * 8);
            u32 qa[4] = {uq.x, uq.y, uq.z, uq.w};
            u32 ka[4] = {uk.x, uk.y, uk.z, uk.w};
            u32 va[4] = {uv.x, uv.y, uv.z, uv.w};
#pragma unroll
            for (int j = 0; j < 4; ++j) {
                q[i * 8 + 2 * j] = bf2f((u16)(qa[j] & 0xffffu));
                q[i * 8 + 2 * j + 1] = bf2f((u16)(qa[j] >> 16));
                Ks[t * 32 + i * 8 + 2 * j] = bf2f((u16)(ka[j] & 0xffffu));
                Ks[t * 32 + i * 8 + 2 * j + 1] = bf2f((u16)(ka[j] >> 16));
                Vs[t * 32 + i * 8 + 2 * j] = bf2f((u16)(va[j] & 0xffffu));
                Vs[t * 32 + i * 8 + 2 * j + 1] = bf2f((u16)(va[j] >> 16));
            }
        }
    }
    __syncthreads();
    if (t >= 49) return;

    float s[49];
    float mx = -1e30f;
    for (int m = 0; m < 49; ++m) {
        float acc = 0.f;
#pragma unroll
        for (int d = 0; d < 32; ++d) acc += q[d] * Ks[m * 32 + d];
        acc *= SCALE_ATTN;
        s[m] = acc;
        mx = fmaxf(mx, acc);
    }
    float sum = 0.f;
    for (int m = 0; m < 49; ++m) { float e = __expf(s[m] - mx); s[m] = e; sum += e; }
    float inv = 1.f / sum;
    float o[32];
#pragma unroll
    for (int d = 0; d < 32; ++d) o[d] = 0.f;
    for (int m = 0; m < 49; ++m) {
        float p = s[m] * inv;
#pragma unroll
        for (int d = 0; d < 32; ++d) o[d] += p * Vs[m * 32 + d];
    }
    u16* op = aout + (size_t)row * 512 + h * 32;
#pragma unroll
    for (int i = 0; i < 4; ++i) {
        uint4 ov;
        ov.x = (u32)f2bf(o[i * 8 + 0]) | ((u32)f2bf(o[i * 8 + 1]) << 16);
        ov.y = (u32)f2bf(o[i * 8 + 2]) | ((u32)f2bf(o[i * 8 + 3]) << 16);
        ov.z = (u32)f2bf(o[i * 8 + 4]) | ((u32)f2bf(o[i * 8 + 5]) << 16);
        ov.w = (u32)f2bf(o[i * 8 + 6]) | ((u32)f2bf(o[i * 8 + 7]) << 16);
        *(uint4*)(op + i * 8) = ov;
    }
}

// ---------------- launch ----------------
extern "C" void kernel_launch(void* const* d_in, const int* in_sizes, int n_in,
                              void* d_out, int out_size, void* d_ws, size_t ws_size,
                              hipStream_t stream) {
    (void)in_sizes; (void)n_in; (void)out_size; (void)ws_size;
    const float* x      = (const float*)d_in[0];
    const float* ln1_g  = (const float*)d_in[1];
    const float* ln1_b  = (const float*)d_in[2];
    const float* qkv_w  = (const float*)d_in[3];
    const float* qkv_b  = (const float*)d_in[4];
    const float* proj_w = (const float*)d_in[5];
    const float* proj_b = (const float*)d_in[6];
    const float* ln2_g  = (const float*)d_in[7];
    const float* ln2_b  = (const float*)d_in[8];
    const float* mlp_w1 = (const float*)d_in[9];
    const float* mlp_b1 = (const float*)d_in[10];
    const float* mlp_w2 = (const float*)d_in[11];
    const float* mlp_b2 = (const float*)d_in[12];
    float* out = (float*)d_out;

    const int M = MROWS;
    char* ws = (char*)d_ws;
    const size_t SZ_H   = (size_t)M * 512 * 2;
    const size_t SZ_X2  = (size_t)M * 512 * 4;
    const size_t SZ_BIG = (size_t)M * 2048 * 2;
    u16*   h    = (u16*)ws;
    float* x2   = (float*)(ws + SZ_H);
    u16*   big  = (u16*)(ws + SZ_H + SZ_X2);
    u16*   qkv_wT  = (u16*)(ws + SZ_H + SZ_X2 + SZ_BIG);
    u16*   proj_wT = qkv_wT + 1536 * 512;
    u16*   w1T     = proj_wT + 512 * 512;
    u16*   w2T     = w1T + 2048 * 512;

    transpose_cast<<<(512 * 1536 + 255) / 256, 256, 0, stream>>>(qkv_w, qkv_wT, 512, 1536);
    transpose_cast<<<(512 * 512 + 255) / 256, 256, 0, stream>>>(proj_w, proj_wT, 512, 512);
    transpose_cast<<<(512 * 2048 + 255) / 256, 256, 0, stream>>>(mlp_w1, w1T, 512, 2048);
    transpose_cast<<<(2048 * 512 + 255) / 256, 256, 0, stream>>>(mlp_w2, w2T, 2048, 512);

    ln_kernel<<<M / 4, 256, 0, stream>>>(x, ln1_g, ln1_b, h);

    gemm_bt<EPI_BF16><<<(M / BM) * (1536 / BN), 512, 0, stream>>>(h, qkv_wT, qkv_b, nullptr, big, M, 1536, 512, 1536 / BN);

    attn_kernel<<<dim3(2048, 16), 64, 0, stream>>>(big, h);

    gemm_bt<EPI_RES_F32><<<(M / BM) * (512 / BN), 512, 0, stream>>>(h, proj_wT, proj_b, x, x2, M, 512, 512, 512 / BN);

    ln_kernel<<<M / 4, 256, 0, stream>>>(x2, ln2_g, ln2_b, h);

    gemm_bt<EPI_GELU_BF16><<<(M / BM) * (2048 / BN), 512, 0, stream>>>(h, w1T, mlp_b1, nullptr, big, M, 2048, 512, 2048 / BN);

    gemm_bt<EPI_RES_F32><<<(M / BM) * (512 / BN), 512, 0, stream>>>(big, w2T, mlp_b2, x2, out, M, 512, 2048, 512 / BN);
}

// Round 6
// 1478.227 us; speedup vs baseline: 1.4060x; 1.0182x over previous
//
#include <hip/hip_runtime.h>
#include <hip/hip_bf16.h>
#include <math.h>

typedef unsigned short u16;
typedef unsigned int u32;
typedef __bf16 bf16x8 __attribute__((ext_vector_type(8)));
typedef float f32x4 __attribute__((ext_vector_type(4)));

#define MROWS 100352   // 32 * 56 * 56
#define CDIM 512
#define SCALE_ATTN 0.17677669529663687f

__device__ __forceinline__ u16 f2bf(float f) {
    u32 u = __float_as_uint(f);
    u32 r = (u + 0x7fffu + ((u >> 16) & 1u)) >> 16;   // RNE
    return (u16)r;
}
__device__ __forceinline__ float bf2f(u16 h) {
    return __uint_as_float(((u32)h) << 16);
}

// ---------------- transpose + cast: fp32 W[K][N] -> bf16 WT[N][K] ----------------
__global__ void transpose_cast(const float* __restrict__ W, u16* __restrict__ WT, int K, int N) {
    int idx = blockIdx.x * 256 + threadIdx.x;
    if (idx >= K * N) return;
    int k = idx / N, n = idx % N;
    WT[(size_t)n * K + k] = f2bf(W[idx]);
}

// ---------------- LayerNorm fp32 -> bf16, one wave per row (C=512) ----------------
__global__ __launch_bounds__(256) void ln_kernel(const float* __restrict__ x, const float* __restrict__ g,
                                                 const float* __restrict__ bta, u16* __restrict__ out) {
    int row = blockIdx.x * 4 + (threadIdx.x >> 6);
    int lane = threadIdx.x & 63;
    const float* xr = x + (size_t)row * CDIM + lane * 8;
    float4 v0 = *(const float4*)xr;
    float4 v1 = *(const float4*)(xr + 4);
    float xv[8] = {v0.x, v0.y, v0.z, v0.w, v1.x, v1.y, v1.z, v1.w};
    float s = 0.f, ss = 0.f;
#pragma unroll
    for (int i = 0; i < 8; ++i) { s += xv[i]; ss += xv[i] * xv[i]; }
#pragma unroll
    for (int o = 1; o < 64; o <<= 1) { s += __shfl_xor(s, o); ss += __shfl_xor(ss, o); }
    float mu = s * (1.f / CDIM);
    float var = ss * (1.f / CDIM) - mu * mu;
    float rs = rsqrtf(var + 1e-6f);
    int c = lane * 8;
    u32 pk[4];
#pragma unroll
    for (int i = 0; i < 4; ++i) {
        float y0 = (xv[2 * i] - mu) * rs * g[c + 2 * i] + bta[c + 2 * i];
        float y1 = (xv[2 * i + 1] - mu) * rs * g[c + 2 * i + 1] + bta[c + 2 * i + 1];
        pk[i] = (u32)f2bf(y0) | ((u32)f2bf(y1) << 16);
    }
    uint4 ov; ov.x = pk[0]; ov.y = pk[1]; ov.z = pk[2]; ov.w = pk[3];
    *(uint4*)(out + (size_t)row * CDIM + c) = ov;
}

// ---------------- bf16 GEMM, 8-phase 256x256, phase-ahead ds_read prefetch ----------------
// 256x256 tile, BK=64, 8 waves (2M x 4N), per-wave 128x64 output.
// LDS 128KB: 2 dbuf x (A 32KB + B 32KB). 4 phases/K-tile, 16 MFMA each.
// ds_reads for phase p+1 issued DURING phase p's MFMA (register double-set afA/afB)
// so the LDS port (~2260 cyc/tile) overlaps the matrix pipe (~2480 cyc/tile).
// B-frags whole tile at boundary. vmcnt(2) discipline; 5 barriers/tile.
#define BM 256
#define BN 256
#define BK 64

enum { EPI_BF16 = 0, EPI_GELU_BF16 = 1, EPI_RES_F32 = 2 };

__device__ __forceinline__ void gload_lds16(const void* g, void* l) {
    __builtin_amdgcn_global_load_lds(
        (const __attribute__((address_space(1))) u32*)g,
        (__attribute__((address_space(3))) u32*)l, 16, 0, 0);
}

#define WAITVM2() asm volatile("s_waitcnt vmcnt(2)" ::: "memory")
#define WAITVM0() asm volatile("s_waitcnt vmcnt(0)" ::: "memory")
#define BARRIER() __builtin_amdgcn_s_barrier()
#define SCHEDBAR() __builtin_amdgcn_sched_barrier(0)

__device__ __forceinline__ float gelu_tanh(float x) {
    float y = 0.7978845608028654f * (x + 0.044715f * x * x * x);
    y = fmaxf(y, -20.f);
    float u = __expf(-2.f * y);
    float th = (1.f - u) / (1.f + u);
    return 0.5f * x * (1.f + th);
}

template <int EPI>
__global__ __launch_bounds__(512, 2) void gemm_bt(const u16* __restrict__ A, const u16* __restrict__ BT,
                                                  const float* __restrict__ bias, const float* __restrict__ res,
                                                  void* __restrict__ outp, int M, int N, int K, int nnb) {
    __shared__ __align__(16) u16 smem[65536];   // 128 KB: A0 A1 | B0 B1 (16384 u16 each)

    const int t = threadIdx.x;
    const int lane = t & 63;
    const int w = t >> 6;
    const int wm = w >> 2, wn = w & 3;   // 2 waves along M, 4 along N

    const int nwg = gridDim.x;
    const int chunk = nwg >> 3;
    const int wg = (blockIdx.x & 7) * chunk + (blockIdx.x >> 3);
    const int m0 = (wg / nnb) * BM;
    const int n0 = (wg % nnb) * BN;

    f32x4 acc[8][4] = {};

    const int r15 = lane & 15;
    const int khalf = (lane >> 4) << 3;
    const int xorv = (r15 & 7) << 3;

    const int srow = t >> 3;                        // 0..63
    const int scol = (((t & 7) ^ (srow & 7)) << 3); // pre-swizzled global column
    const u16* Ag = A + (size_t)(m0 + srow) * K + scol;
    const u16* Bg = BT + (size_t)(n0 + srow) * K + scol;

    const int nt = K / BK;

#define STAGE_HALF(h_, tile_, dd_)                                                   \
    {                                                                                \
        const int kt_ = (tile_) * BK;                                                \
        u16* dst_ = smem + ((h_) < 2 ? 0 : 32768) + (dd_) * 16384 + ((h_) & 1) * 8192; \
        const u16* src_ = (((h_) < 2) ? Ag : Bg) + (size_t)(((h_) & 1) * 128) * K + kt_; \
        gload_lds16(src_, &dst_[t * 8]);                                             \
        gload_lds16(src_ + (size_t)64 * K, &dst_[4096 + t * 8]);                     \
    }

#define READ_A(af_, p_)                                                              \
    {                                                                                \
        _Pragma("unroll")                                                            \
        for (int q = 0; q < 2; ++q)                                                  \
            _Pragma("unroll")                                                        \
            for (int kk = 0; kk < 2; ++kk)                                           \
                af_[q][kk] = *(const bf16x8*)&As[(wm * 128 + (2 * (p_) + q) * 16 + r15) * BK + ((kk * 32 + khalf) ^ xorv)]; \
    }

#define MFMA_CLUSTER(af_, p_)                                                        \
    {                                                                                \
        __builtin_amdgcn_s_setprio(1);                                               \
        _Pragma("unroll")                                                            \
        for (int kk = 0; kk < 2; ++kk)                                               \
            _Pragma("unroll")                                                        \
            for (int q = 0; q < 2; ++q)                                              \
                _Pragma("unroll")                                                    \
                for (int ni = 0; ni < 4; ++ni)                                       \
                    acc[2 * (p_) + q][ni] = __builtin_amdgcn_mfma_f32_16x16x32_bf16(af_[q][kk], bfr[ni][kk], acc[2 * (p_) + q][ni], 0, 0, 0); \
        __builtin_amdgcn_s_setprio(0);                                               \
    }

#define SGB_PHASE(nvm_, nds_)                                                        \
    {                                                                                \
        if (nvm_) __builtin_amdgcn_sched_group_barrier(0x10, nvm_, 0);               \
        if (nds_) __builtin_amdgcn_sched_group_barrier(0x100, nds_, 0);              \
        __builtin_amdgcn_sched_group_barrier(0x8, 16, 0);                            \
    }

    // prologue: stage all 4 halves of tile 0 into dbuf 0
    STAGE_HALF(0, 0, 0); STAGE_HALF(1, 0, 0); STAGE_HALF(2, 0, 0); STAGE_HALF(3, 0, 0);

    for (int tt = 0; tt < nt; ++tt) {
        const int d = tt & 1;
        const u16* As = smem + d * 16384;
        const u16* Bs = smem + 32768 + d * 16384;
        bf16x8 bfr[4][2];
        bf16x8 afA[2][2], afB[2][2];
        const bool pf = (tt + 1 < nt);

        // ---- tile boundary ----
        if (pf) STAGE_HALF(0, tt + 1, d ^ 1);
        if (pf) WAITVM2(); else WAITVM0();
        BARRIER();        // tile tt LDS-visible to all waves
        SCHEDBAR();       // no ds_read hoists above this point

        // boundary reads: whole-tile B frags + phase-0 A frags
#pragma unroll
        for (int ni = 0; ni < 4; ++ni)
#pragma unroll
            for (int kk = 0; kk < 2; ++kk)
                bfr[ni][kk] = *(const bf16x8*)&Bs[(wn * 64 + ni * 16 + r15) * BK + ((kk * 32 + khalf) ^ xorv)];
        READ_A(afA, 0);

        // ---- phase 0: stage h1, prefetch p1 frags, MFMA p0 ----
        if (pf) STAGE_HALF(1, tt + 1, d ^ 1);
        READ_A(afB, 1);
        MFMA_CLUSTER(afA, 0);
        SGB_PHASE(2, 16);
        BARRIER(); SCHEDBAR();

        // ---- phase 1: stage h2, prefetch p2, MFMA p1 ----
        if (pf) STAGE_HALF(2, tt + 1, d ^ 1);
        READ_A(afA, 2);
        MFMA_CLUSTER(afB, 1);
        SGB_PHASE(2, 4);
        BARRIER(); SCHEDBAR();

        // ---- phase 2: stage h3, prefetch p3, MFMA p2 ----
        if (pf) STAGE_HALF(3, tt + 1, d ^ 1);
        READ_A(afB, 3);
        MFMA_CLUSTER(afA, 2);
        SGB_PHASE(2, 4);
        BARRIER(); SCHEDBAR();

        // ---- phase 3: pure MFMA ----
        MFMA_CLUSTER(afB, 3);
        SGB_PHASE(0, 0);
        BARRIER();        // close tile: all waves' reads of dbuf d retired before
        SCHEDBAR();       // any wave issues the overwriting stage next iteration
    }
#undef STAGE_HALF
#undef READ_A
#undef MFMA_CLUSTER
#undef SGB_PHASE

    // ---- coalesced epilogue: per-wave LDS staging (wave-private, 76-float pad) ----
    float* ep = (float*)smem + w * (16 * 76);
    const int lg = lane >> 4;
#pragma unroll
    for (int mi = 0; mi < 8; ++mi) {
#pragma unroll
        for (int ni = 0; ni < 4; ++ni)
#pragma unroll
            for (int j = 0; j < 4; ++j)
                ep[(lg * 4 + j) * 76 + ni * 16 + r15] = acc[mi][ni][j];
#pragma unroll
        for (int p = 0; p < 4; ++p) {
            int lr = p * 4 + lg;
            f32x4 v = *(f32x4*)&ep[lr * 76 + r15 * 4];
            int grow = m0 + wm * 128 + mi * 16 + lr;
            int gcol = n0 + wn * 64 + r15 * 4;
            float4 bv = *(const float4*)&bias[gcol];
            float o0 = v[0] + bv.x, o1 = v[1] + bv.y, o2 = v[2] + bv.z, o3 = v[3] + bv.w;
            if (EPI == EPI_GELU_BF16) {
                o0 = gelu_tanh(o0); o1 = gelu_tanh(o1); o2 = gelu_tanh(o2); o3 = gelu_tanh(o3);
            }
            if (EPI == EPI_RES_F32) {
                size_t off = (size_t)grow * N + gcol;
                float4 rv = *(const float4*)&res[off];
                float4 ov = make_float4(o0 + rv.x, o1 + rv.y, o2 + rv.z, o3 + rv.w);
                *(float4*)((float*)outp + off) = ov;
            } else {
                uint2 ov;
                ov.x = (u32)f2bf(o0) | ((u32)f2bf(o1) << 16);
                ov.y = (u32)f2bf(o2) | ((u32)f2bf(o3) << 16);
                *(uint2*)((u16*)outp + (size_t)grow * N + gcol) = ov;
            }
        }
    }
}

// ---------------- windowed attention: one wave per (window, head) ----------------
__global__ __launch_bounds__(64) void attn_kernel(const u16* __restrict__ qkv, u16* __restrict__ aout) {
    __shared__ float Ks[49 * 32];
    __shared__ float Vs[49 * 32];
    const int wdw = blockIdx.x;
    const int h = blockIdx.y;
    const int t = threadIdx.x;
    const int b = wdw >> 6, wy = (wdw >> 3) & 7, wx = wdw & 7;

    int row = 0;
    float q[32];
    if (t < 49) {
        int py = t / 7, px = t % 7;
        row = b * 3136 + (wy * 7 + py) * 56 + (wx * 7 + px);
        const u16* bp = qkv + (size_t)row * 1536 + h * 32;
#pragma unroll
        for (int i = 0; i < 4; ++i) {
            uint4 uq = *(const uint4*)(bp + i * 8);
            uint4 uk = *(const uint4*)(bp + 512 + i * 8);
            uint4 uv = *(const uint4*)(bp + 1024 + i * 8);
            u32 qa[4] = {uq.x, uq.y, uq.z, uq.w};
            u32 ka[4] = {uk.x, uk.y, uk.z, uk.w};
            u32 va[4] = {uv.x, uv.y, uv.z, uv.w};
#pragma unroll
            for (int j = 0; j < 4; ++j) {
                q[i * 8 + 2 * j] = bf2f((u16)(qa[j] & 0xffffu));
                q[i * 8 + 2 * j + 1] = bf2f((u16)(qa[j] >> 16));
                Ks[t * 32 + i * 8 + 2 * j] = bf2f((u16)(ka[j] & 0xffffu));
                Ks[t * 32 + i * 8 + 2 * j + 1] = bf2f((u16)(ka[j] >> 16));
                Vs[t * 32 + i * 8 + 2 * j] = bf2f((u16)(va[j] & 0xffffu));
                Vs[t * 32 + i * 8 + 2 * j + 1] = bf2f((u16)(va[j] >> 16));
            }
        }
    }
    __syncthreads();
    if (t >= 49) return;

    float s[49];
    float mx = -1e30f;
    for (int m = 0; m < 49; ++m) {
        float acc = 0.f;
#pragma unroll
        for (int d = 0; d < 32; ++d) acc += q[d] * Ks[m * 32 + d];
        acc *= SCALE_ATTN;
        s[m] = acc;
        mx = fmaxf(mx, acc);
    }
    float sum = 0.f;
    for (int m = 0; m < 49; ++m) { float e = __expf(s[m] - mx); s[m] = e; sum += e; }
    float inv = 1.f / sum;
    float o[32];
#pragma unroll
    for (int d = 0; d < 32; ++d) o[d] = 0.f;
    for (int m = 0; m < 49; ++m) {
        float p = s[m] * inv;
#pragma unroll
        for (int d = 0; d < 32; ++d) o[d] += p * Vs[m * 32 + d];
    }
    u16* op = aout + (size_t)row * 512 + h * 32;
#pragma unroll
    for (int i = 0; i < 4; ++i) {
        uint4 ov;
        ov.x = (u32)f2bf(o[i * 8 + 0]) | ((u32)f2bf(o[i * 8 + 1]) << 16);
        ov.y = (u32)f2bf(o[i * 8 + 2]) | ((u32)f2bf(o[i * 8 + 3]) << 16);
        ov.z = (u32)f2bf(o[i * 8 + 4]) | ((u32)f2bf(o[i * 8 + 5]) << 16);
        ov.w = (u32)f2bf(o[i * 8 + 6]) | ((u32)f2bf(o[i * 8 + 7]) << 16);
        *(uint4*)(op + i * 8) = ov;
    }
}

// ---------------- launch ----------------
extern "C" void kernel_launch(void* const* d_in, const int* in_sizes, int n_in,
                              void* d_out, int out_size, void* d_ws, size_t ws_size,
                              hipStream_t stream) {
    (void)in_sizes; (void)n_in; (void)out_size; (void)ws_size;
    const float* x      = (const float*)d_in[0];
    const float* ln1_g  = (const float*)d_in[1];
    const float* ln1_b  = (const float*)d_in[2];
    const float* qkv_w  = (const float*)d_in[3];
    const float* qkv_b  = (const float*)d_in[4];
    const float* proj_w = (const float*)d_in[5];
    const float* proj_b = (const float*)d_in[6];
    const float* ln2_g  = (const float*)d_in[7];
    const float* ln2_b  = (const float*)d_in[8];
    const float* mlp_w1 = (const float*)d_in[9];
    const float* mlp_b1 = (const float*)d_in[10];
    const float* mlp_w2 = (const float*)d_in[11];
    const float* mlp_b2 = (const float*)d_in[12];
    float* out = (float*)d_out;

    const int M = MROWS;
    char* ws = (char*)d_ws;
    const size_t SZ_H   = (size_t)M * 512 * 2;
    const size_t SZ_X2  = (size_t)M * 512 * 4;
    const size_t SZ_BIG = (size_t)M * 2048 * 2;
    u16*   h    = (u16*)ws;
    float* x2   = (float*)(ws + SZ_H);
    u16*   big  = (u16*)(ws + SZ_H + SZ_X2);
    u16*   qkv_wT  = (u16*)(ws + SZ_H + SZ_X2 + SZ_BIG);
    u16*   proj_wT = qkv_wT + 1536 * 512;
    u16*   w1T     = proj_wT + 512 * 512;
    u16*   w2T     = w1T + 2048 * 512;

    transpose_cast<<<(512 * 1536 + 255) / 256, 256, 0, stream>>>(qkv_w, qkv_wT, 512, 1536);
    transpose_cast<<<(512 * 512 + 255) / 256, 256, 0, stream>>>(proj_w, proj_wT, 512, 512);
    transpose_cast<<<(512 * 2048 + 255) / 256, 256, 0, stream>>>(mlp_w1, w1T, 512, 2048);
    transpose_cast<<<(2048 * 512 + 255) / 256, 256, 0, stream>>>(mlp_w2, w2T, 2048, 512);

    ln_kernel<<<M / 4, 256, 0, stream>>>(x, ln1_g, ln1_b, h);

    gemm_bt<EPI_BF16><<<(M / BM) * (1536 / BN), 512, 0, stream>>>(h, qkv_wT, qkv_b, nullptr, big, M, 1536, 512, 1536 / BN);

    attn_kernel<<<dim3(2048, 16), 64, 0, stream>>>(big, h);

    gemm_bt<EPI_RES_F32><<<(M / BM) * (512 / BN), 512, 0, stream>>>(h, proj_wT, proj_b, x, x2, M, 512, 512, 512 / BN);

    ln_kernel<<<M / 4, 256, 0, stream>>>(x2, ln2_g, ln2_b, h);

    gemm_bt<EPI_GELU_BF16><<<(M / BM) * (2048 / BN), 512, 0, stream>>>(h, w1T, mlp_b1, nullptr, big, M, 2048, 512, 2048 / BN);

    gemm_bt<EPI_RES_F32><<<(M / BM) * (512 / BN), 512, 0, stream>>>(big, w2T, mlp_b2, x2, out, M, 512, 2048, 512 / BN);
}